// Round 8
// baseline (579.284 us; speedup 1.0000x reference)
//
#include <hip/hip_runtime.h>

#define B_ 8
#define N_ 16384
#define F_ 6
#define M_ 128
#define K_ 16
#define D_ 768

typedef unsigned short u16;
typedef unsigned int u32;
typedef unsigned long long u64;
typedef __attribute__((ext_vector_type(8))) short short8;
typedef __attribute__((ext_vector_type(4))) float f32x4;
typedef __attribute__((ext_vector_type(2))) float f32x2;

__device__ __forceinline__ u16 f2bf(float f){
  union { float f; u32 i; } v; v.f = f;
  u32 x = v.i;
  u32 r = x + 0x7FFFu + ((x >> 16) & 1u);
  return (u16)(r >> 16);
}

// async 16B global->LDS (dest = wave-uniform base + lane*16)
__device__ __forceinline__ void ld_g2l(const u16* g, u16* l){
  __builtin_amdgcn_global_load_lds((const __attribute__((address_space(1))) u32*)g,
                                   (__attribute__((address_space(3))) u32*)l, 16, 0, 0);
}

// packed dual-f32 ops (CDNA2+ full-rate packed fp32; bit-exact IEEE per lane)
__device__ __forceinline__ f32x2 pkadd(f32x2 a, f32x2 b){
  f32x2 d; asm("v_pk_add_f32 %0, %1, %2" : "=v"(d) : "v"(a), "v"(b)); return d;
}
__device__ __forceinline__ f32x2 pkmul(f32x2 a, f32x2 b){
  f32x2 d; asm("v_pk_mul_f32 %0, %1, %2" : "=v"(d) : "v"(a), "v"(b)); return d;
}

// VOLATILE asm 16B load: result cannot be rematerialized from memory by LLVM.
__device__ __forceinline__ f32x4 ld_x4(const float* p){
  f32x4 r;
  asm volatile("global_load_dwordx4 %0, %1, off" : "=v"(r) : "v"(p) : "memory");
  return r;
}

// DPP self-max step: v = max(v, lane-shifted v). Full-rate VALU — no LDS, no lgkmcnt.
template<int CTRL>
__device__ __forceinline__ float dppmax(float v){
  union { float f; int i; } a, r;
  a.f = v;
  r.i = __builtin_amdgcn_update_dpp(a.i, a.i, CTRL, 0xF, 0xF, false);
  return fmaxf(v, r.f);
}

// ---------------- all weights f32 -> bf16 transposed [n][k], ONE kernel ----------------
__global__ __launch_bounds__(256) void conv_all(const float* __restrict__ W1,
                                                const float* __restrict__ W2,
                                                const float* __restrict__ W3,
                                                const float* __restrict__ Wn0,
                                                const float* __restrict__ Wn1,
                                                u16* __restrict__ Wb){
  __shared__ u16 tile[64][65];
  int blk = blockIdx.x;
  const float* W; u16* WT; int K, N, lb;
  if      (blk < 32)  { W = W1;  WT = Wb;           K = 256; N = 512; lb = blk; }
  else if (blk < 128) { W = W2;  WT = Wb + 131072;  K = 512; N = 768; lb = blk - 32; }
  else if (blk < 272) { W = W3;  WT = Wb + 524288;  K = 768; N = 768; lb = blk - 128; }
  else if (blk < 416) { W = Wn0; WT = Wb + 1114112; K = 768; N = 768; lb = blk - 272; }
  else                { W = Wn1; WT = Wb + 1703936; K = 768; N = 768; lb = blk - 416; }
  int tiles_n = N >> 6;
  int tk = lb / tiles_n, tn = lb % tiles_n;
  int k0 = tk << 6, n0 = tn << 6;
  int t = threadIdx.x;
#pragma unroll
  for (int q = 0; q < 16; q++){
    int idx = q * 256 + t;
    int kk = idx >> 6, nn = idx & 63;
    tile[kk][nn] = f2bf(W[(size_t)(k0 + kk) * N + n0 + nn]);
  }
  __syncthreads();
#pragma unroll
  for (int q = 0; q < 16; q++){
    int idx = q * 256 + t;
    int nn = idx >> 6, kk = idx & 63;
    WT[(size_t)(n0 + nn) * K + k0 + kk] = tile[kk][nn];
  }
}

// ---------------- FPS: xy in LDS (conflict-free interleave), zw+md in 48 regs ----------------
// r0-r7 invariant: the allocator refuses >92 arch VGPRs -> 160-reg state always round-trips
// through L2/scratch (256KB/step / 56B/cy = 4680cy = the measured step). Fix: demand only
// 48 pinned regs (pzw volatile + md) and serve x,y from LDS at 128B/cy on-CU.
// Thread t owns CONTIGUOUS points [16t,16t+16) -> lane order == index order; ties resolve
// by lowest lane (ballot) then lowest wave (strict > scan) == jnp.argmax first-max.
// Exact math: d = ((dx*dx + dy*dy) + dz*dz) + dw*dw (contract off), md = min(md, d).
// LDS slot(k,t) = k*1024 + t: a wave's reads are 64 consecutive 8B slots (no bank conflict).
#define FPT 16   // points per thread: 16384 / 1024
__global__ __launch_bounds__(1024) __attribute__((amdgpu_waves_per_eu(4, 4)))
void fps_block(const float* __restrict__ coords, float* __restrict__ cent){
#pragma clang fp contract(off)
  __shared__ f32x2 sxy[N_];          // 128 KB, interleaved slot = k*1024 + t
  __shared__ f32x4 swv4[2][4];       // 16 wave maxima as 4x f32x4 (b128 scan reads)
  __shared__ f32x4 swc[2][16];       // winning candidate coords per wave
  int b = blockIdx.x;
  int t = threadIdx.x;
  int lane = t & 63, wave = t >> 6;
  const float* cb = coords + (size_t)b * N_ * 5;
  const int base = t << 4;                        // first point index owned by this thread
  f32x2 pzw[FPT];
  float md[FPT];
#pragma unroll
  for (int k = 0; k < FPT; k++){
    f32x4 q = ld_x4(cb + (size_t)(base + k) * 5 + 1);   // (x,y,z,w), volatile
    asm volatile("s_waitcnt vmcnt(0)" ::: "memory");
    sxy[k * 1024 + t] = (f32x2){q[0], q[1]};
    pzw[k] = (f32x2){q[2], q[3]};
    md[k] = 1e30f;
  }
  __builtin_amdgcn_sched_barrier(0);
  float cx = cb[1], cy = cb[2], cz = cb[3], ct = cb[4];
  if (t == 0){
    float* c0 = cent + (size_t)b * M_ * 4;
    c0[0]=cx; c0[1]=cy; c0[2]=cz; c0[3]=ct;
  }
  for (int step = 1; step < M_; step++){
    // x - c computed as x + (-c): IEEE-identical, enables plain v_pk_add
    f32x2 ncxy = (f32x2){-cx, -cy};
    f32x2 nczw = (f32x2){-cz, -ct};
    float bv = -1.0f; int bl = 0;
#pragma unroll
    for (int k = 0; k < FPT; k++){
      f32x2 xy = sxy[k * 1024 + t];                // ds_read_b64, conflict-free
      f32x2 dxy = pkadd(xy, ncxy);                 // (dx, dy)
      f32x2 dzw = pkadd(pzw[k], nczw);             // (dz, dw)
      f32x2 s1 = pkmul(dxy, dxy);                  // (dx*dx, dy*dy)
      f32x2 s2 = pkmul(dzw, dzw);                  // (dz*dz, dw*dw)
      float s = ((s1[0] + s1[1]) + s2[0]) + s2[1]; // reference rounding order
      float m = fminf(s, md[k]);
      md[k] = m;
      if (m > bv){ bv = m; bl = k; }               // ascending-index first-max
    }
    // ---- wave argmax: 6 DPP fmax levels -> lane 63 holds wave max ----
    float r = bv;
    r = dppmax<0x111>(r);        // row_shr:1
    r = dppmax<0x112>(r);        // row_shr:2
    r = dppmax<0x114>(r);        // row_shr:4
    r = dppmax<0x118>(r);        // row_shr:8
    r = dppmax<0x142>(r);        // row_bcast:15
    r = dppmax<0x143>(r);        // row_bcast:31
    union { float f; int i; } rm; rm.f = r;
    union { int i; float f; } wmu; wmu.i = __builtin_amdgcn_readlane(rm.i, 63);
    float wmax = wmu.f;                            // uniform
    u64 wmask = __ballot(bv == wmax);
    int srcL = (int)__ffsll((unsigned long long)wmask) - 1;  // lowest lane = lowest index
    // select winner's zw by compile-time-indexed cndmask chain (rule #20: no dyn reg index)
    f32x2 zwsel = pzw[0];
#pragma unroll
    for (int k = 1; k < FPT; k++) zwsel = (bl == k) ? pzw[k] : zwsel;
    int par = step & 1;
    if (lane == srcL){
      f32x2 xyw = sxy[bl * 1024 + t];              // winner's xy from own LDS slot
      ((float*)&swv4[par])[wave] = bv;
      swc[par][wave] = (f32x4){xyw[0], xyw[1], zwsel[0], zwsel[1]};
    }
    __syncthreads();                               // only barrier per step
    // ---- block combine: 4x b128 broadcast reads + strict-greater scan over 16 waves ----
    float fv; int fw = 0;
    {
      f32x4 v0 = swv4[par][0], v1 = swv4[par][1], v2 = swv4[par][2], v3 = swv4[par][3];
      fv = v0[0];
#pragma unroll
      for (int j = 1; j < 4; j++) if (v0[j] > fv){ fv = v0[j]; fw = j; }
#pragma unroll
      for (int j = 0; j < 4; j++) if (v1[j] > fv){ fv = v1[j]; fw = 4 + j; }
#pragma unroll
      for (int j = 0; j < 4; j++) if (v2[j] > fv){ fv = v2[j]; fw = 8 + j; }
#pragma unroll
      for (int j = 0; j < 4; j++) if (v3[j] > fv){ fv = v3[j]; fw = 12 + j; }
    }
    f32x4 wc = swc[par][fw];                       // broadcast b128 read
    cx = wc[0]; cy = wc[1]; cz = wc[2]; ct = wc[3];
    if (t == 0){
      float* cr = cent + ((size_t)b * M_ + step) * 4;
      cr[0]=cx; cr[1]=cy; cr[2]=cz; cr[3]=ct;
    }
  }
}

// ---------------- stable rank by centroid time; relabel early; f32 outputs ----------------
__global__ __launch_bounds__(128) void rank_scatter(const float* __restrict__ cent_fps,
                                                    float* __restrict__ cent_sorted,
                                                    float* __restrict__ out,
                                                    size_t out_elems){
  int b = blockIdx.x, m = threadIdx.x;
  __shared__ float tt[M_];
  const float* row = cent_fps + ((size_t)b * M_ + m) * 4;
  float x=row[0], y=row[1], z=row[2], w=row[3];
  tt[m] = w;
  __syncthreads();
  int rank = 0;
  for (int j = 0; j < M_; j++){
    float tj = tt[j];
    if (tj < w || (tj == w && j < m)) rank++;       // stable argsort semantics
  }
  float* dst = cent_sorted + ((size_t)b * M_ + rank) * 4;
  dst[0]=x; dst[1]=y; dst[2]=z; dst[3]=w;
  size_t co = (size_t)B_ * M_ * D_ + ((size_t)b * M_ + rank) * 4;
  if (co + 3 < out_elems){
    out[co+0]=x; out[co+1]=y; out[co+2]=z; out[co+3]=w;
  }
  size_t mo = (size_t)B_ * M_ * D_ + (size_t)B_ * M_ * 4 + (size_t)b * M_ + m;
  if (mo < out_elems) out[mo] = 1.0f;              // mask = True -> 1.0f
}

// ---------------- kNN: f32, np op order, stable-min extraction ----------------
#define KNT 512
#define KPT 32
__global__ __launch_bounds__(512) void knn_kernel(const float* __restrict__ coords,
                                                  const float* __restrict__ cent,
                                                  int* __restrict__ knn){
#pragma clang fp contract(off)
  int cm = blockIdx.x;
  int b = cm >> 7;
  const float* cb = coords + (size_t)b * N_ * 5;
  int t = threadIdx.x;
  float cx=cent[cm*4+0], cy=cent[cm*4+1], cz=cent[cm*4+2], ct=cent[cm*4+3];
  float dist[KPT];
#pragma unroll
  for (int j = 0; j < KPT; j++){
    size_t i = t + j * KNT;
    float dx=cb[i*5+1]-cx, dy=cb[i*5+2]-cy, dz=cb[i*5+3]-cz, dw=cb[i*5+4]-ct;
    float d = ((dx*dx + dy*dy) + dz*dz) + dw*dw;
    dist[j] = sqrtf(d);                            // IEEE f32 sqrt = np.sqrt(f32)
  }
  __shared__ float s_wv[8];
  __shared__ int s_wi[8];
  __shared__ int s_bi;
  for (int r = 0; r < K_; r++){
    float bv = 3e38f; int bi = 1 << 30;
#pragma unroll
    for (int j = 0; j < KPT; j++){
      int i = t + j * KNT;
      float v = dist[j];
      if (v < bv){ bv = v; bi = i; }               // first-min kept
    }
#pragma unroll
    for (int off = 32; off > 0; off >>= 1){
      float ov = __shfl_down(bv, off);
      int oi = __shfl_down(bi, off);
      if (ov < bv || (ov == bv && oi < bi)){ bv = ov; bi = oi; }
    }
    if ((t & 63) == 0){ s_wv[t >> 6] = bv; s_wi[t >> 6] = bi; }
    __syncthreads();
    if (t == 0){
      float fv = s_wv[0]; int fi = s_wi[0];
      for (int w = 1; w < 8; w++){
        float wv = s_wv[w]; int wi = s_wi[w];
        if (wv < fv || (wv == fv && wi < fi)){ fv = wv; fi = wi; }
      }
      s_bi = fi;
      knn[(size_t)cm * K_ + r] = fi & (N_ - 1);
    }
    __syncthreads();
    int wi = s_bi;
#pragma unroll
    for (int j = 0; j < KPT; j++){
      if (t + j * KNT == wi) dist[j] = 3e38f;
    }
  }
}

// ---------------- gather + layer0: 32 rows/block, W0/b0/features LDS-staged ----------------
__global__ __launch_bounds__(256) void gather_l0(const float* __restrict__ feat,
                                                 const int* __restrict__ knn,
                                                 const float* __restrict__ W0,
                                                 const float* __restrict__ b0,
                                                 u16* __restrict__ h1,
                                                 int rowBase){
  __shared__ float sW[F_][256];
  __shared__ float sb[256];
  __shared__ float sfa[32][F_];
  int t = threadIdx.x;
#pragma unroll
  for (int k = 0; k < F_; k++) sW[k][t] = W0[k * 256 + t];
  sb[t] = b0[t];
  if (t < 32 * F_){
    int r = t / F_, k = t % F_;
    int grow = rowBase + blockIdx.x * 32 + r;
    int bb = grow >> 11;                          // /(M*K)=2048
    int idx = knn[grow] & (N_ - 1);
    sfa[r][k] = feat[((size_t)bb * N_ + idx) * F_ + k];
  }
  __syncthreads();
#pragma unroll 4
  for (int r = 0; r < 32; r++){
    float acc = sb[t];
#pragma unroll
    for (int k = 0; k < F_; k++) acc = fmaf(sfa[r][k], sW[k][t], acc);
    int lrow = blockIdx.x * 32 + r;
    h1[(size_t)lrow * 256 + t] = f2bf(fmaxf(acc, 0.0f));
  }
}

// ---------------- bf16 MFMA GEMM (128x128), async global->LDS staging ----------------
// Unpadded [128][32] rows (64B): dest = wave-uniform base + lane*16 (m97 layout).
template<int RELU, int OUTF32>
__global__ __launch_bounds__(256) void gemm_bf16(const u16* __restrict__ A,
                                                 const u16* __restrict__ WT,
                                                 const float* __restrict__ bias,
                                                 void* __restrict__ Cv,
                                                 int Kd, int Nd){
  __shared__ u16 As[128][32];
  __shared__ u16 Bs[128][32];
  const int t = threadIdx.x;
  const int bm = blockIdx.y << 7;
  const int bn = blockIdx.x << 7;
  const int wave = t >> 6;
  const int lane = t & 63;
  const int wm = (wave & 1) << 6;
  const int wn = (wave >> 1) << 6;
  const int lm = lane & 15;
  const int lk = (lane >> 4) << 3;
  u16* AsF = &As[0][0];
  u16* BsF = &Bs[0][0];
  const int wbase = wave << 6;               // t - lane
  f32x4 acc[4][4] = {};
  for (int k0 = 0; k0 < Kd; k0 += 32){
#pragma unroll
    for (int it = 0; it < 2; it++){
      int slot = t + (it << 8);
      int r = slot >> 2;
      int c = (slot & 3) << 3;
      int dst = (wbase + (it << 8)) << 3;    // u16 elements; +lane*16B by HW
      ld_g2l(A  + (size_t)(bm + r) * Kd + k0 + c, AsF + dst);
      ld_g2l(WT + (size_t)(bn + r) * Kd + k0 + c, BsF + dst);
    }
    __syncthreads();
    short8 af[4], bfr[4];
#pragma unroll
    for (int mt = 0; mt < 4; mt++) af[mt] = *(const short8*)&As[wm + (mt << 4) + lm][lk];
#pragma unroll
    for (int nt = 0; nt < 4; nt++) bfr[nt] = *(const short8*)&Bs[wn + (nt << 4) + lm][lk];
#pragma unroll
    for (int mt = 0; mt < 4; mt++)
#pragma unroll
      for (int nt = 0; nt < 4; nt++)
        acc[mt][nt] = __builtin_amdgcn_mfma_f32_16x16x32_bf16(af[mt], bfr[nt], acc[mt][nt], 0, 0, 0);
    __syncthreads();
  }
#pragma unroll
  for (int nt = 0; nt < 4; nt++){
    int n = bn + wn + (nt << 4) + lm;
    float bia = bias[n];
#pragma unroll
    for (int mt = 0; mt < 4; mt++){
#pragma unroll
      for (int r2 = 0; r2 < 4; r2++){
        int m = bm + wm + (mt << 4) + ((lane >> 4) << 2) + r2;
        float v = acc[mt][nt][r2] + bia;
        if (RELU) v = fmaxf(v, 0.0f);
        if (OUTF32) ((float*)Cv)[(size_t)m * Nd + n] = v;
        else        ((u16*)Cv)[(size_t)m * Nd + n] = f2bf(v);
      }
    }
  }
}

// ---------------- bf16 MFMA GEMM (64x64), async staging, token GEMMs ----------------
template<int RELU, int OUTF32>
__global__ __launch_bounds__(256) void gemm64(const u16* __restrict__ A,
                                              const u16* __restrict__ WT,
                                              const float* __restrict__ bias,
                                              void* __restrict__ Cv,
                                              int Kd, int Nd){
  __shared__ u16 As[64][32];
  __shared__ u16 Bs[64][32];
  const int t = threadIdx.x;
  const int bm = blockIdx.y << 6;
  const int bn = blockIdx.x << 6;
  const int wave = t >> 6;
  const int lane = t & 63;
  const int wm = (wave & 1) << 5;
  const int wn = (wave >> 1) << 5;
  const int lm = lane & 15;
  const int lk = (lane >> 4) << 3;
  u16* AsF = &As[0][0];
  u16* BsF = &Bs[0][0];
  const int wbase = wave << 6;
  f32x4 acc[2][2] = {};
  for (int k0 = 0; k0 < Kd; k0 += 32){
    {
      int r = t >> 2;
      int c = (t & 3) << 3;
      int dst = wbase << 3;
      ld_g2l(A  + (size_t)(bm + r) * Kd + k0 + c, AsF + dst);
      ld_g2l(WT + (size_t)(bn + r) * Kd + k0 + c, BsF + dst);
    }
    __syncthreads();
    short8 af[2], bfr[2];
#pragma unroll
    for (int mt = 0; mt < 2; mt++) af[mt] = *(const short8*)&As[wm + (mt << 4) + lm][lk];
#pragma unroll
    for (int nt = 0; nt < 2; nt++) bfr[nt] = *(const short8*)&Bs[wn + (nt << 4) + lm][lk];
#pragma unroll
    for (int mt = 0; mt < 2; mt++)
#pragma unroll
      for (int nt = 0; nt < 2; nt++)
        acc[mt][nt] = __builtin_amdgcn_mfma_f32_16x16x32_bf16(af[mt], bfr[nt], acc[mt][nt], 0, 0, 0);
    __syncthreads();
  }
#pragma unroll
  for (int nt = 0; nt < 2; nt++){
    int n = bn + wn + (nt << 4) + lm;
    float bia = bias[n];
#pragma unroll
    for (int mt = 0; mt < 2; mt++){
#pragma unroll
      for (int r2 = 0; r2 < 4; r2++){
        int m = bm + wm + (mt << 4) + ((lane >> 4) << 2) + r2;
        float v = acc[mt][nt][r2] + bia;
        if (RELU) v = fmaxf(v, 0.0f);
        if (OUTF32) ((float*)Cv)[(size_t)m * Nd + n] = v;
        else        ((u16*)Cv)[(size_t)m * Nd + n] = f2bf(v);
      }
    }
  }
}

// ---------------- GEMM + fused max-pool (128x128), async staging ----------------
__global__ __launch_bounds__(256) void gemm_pool(const u16* __restrict__ A,
                                                 const u16* __restrict__ WT,
                                                 const float* __restrict__ bias,
                                                 u16* __restrict__ pooled,
                                                 int Kd, int Nd, int groupBase){
  __shared__ u16 As[128][32];
  __shared__ u16 Bs[128][32];
  const int t = threadIdx.x;
  const int bm = blockIdx.y << 7;
  const int bn = blockIdx.x << 7;
  const int wave = t >> 6;
  const int lane = t & 63;
  const int wm = (wave & 1) << 6;
  const int wn = (wave >> 1) << 6;
  const int lm = lane & 15;
  const int lk = (lane >> 4) << 3;
  u16* AsF = &As[0][0];
  u16* BsF = &Bs[0][0];
  const int wbase = wave << 6;
  f32x4 acc[4][4] = {};
  for (int k0 = 0; k0 < Kd; k0 += 32){
#pragma unroll
    for (int it = 0; it < 2; it++){
      int slot = t + (it << 8);
      int r = slot >> 2;
      int c = (slot & 3) << 3;
      int dst = (wbase + (it << 8)) << 3;
      ld_g2l(A  + (size_t)(bm + r) * Kd + k0 + c, AsF + dst);
      ld_g2l(WT + (size_t)(bn + r) * Kd + k0 + c, BsF + dst);
    }
    __syncthreads();
    short8 af[4], bfr[4];
#pragma unroll
    for (int mt = 0; mt < 4; mt++) af[mt] = *(const short8*)&As[wm + (mt << 4) + lm][lk];
#pragma unroll
    for (int nt = 0; nt < 4; nt++) bfr[nt] = *(const short8*)&Bs[wn + (nt << 4) + lm][lk];
#pragma unroll
    for (int mt = 0; mt < 4; mt++)
#pragma unroll
      for (int nt = 0; nt < 4; nt++)
        acc[mt][nt] = __builtin_amdgcn_mfma_f32_16x16x32_bf16(af[mt], bfr[nt], acc[mt][nt], 0, 0, 0);
    __syncthreads();
  }
  // each (mt) tile's 16 rows are exactly one pooling group
#pragma unroll
  for (int nt = 0; nt < 4; nt++){
    int n = bn + wn + (nt << 4) + lm;
    float bia = bias[n];
#pragma unroll
    for (int mt = 0; mt < 4; mt++){
      f32x4 a = acc[mt][nt];
      float v = fmaxf(fmaxf(a[0], a[1]), fmaxf(a[2], a[3]));
      v = fmaxf(v, __shfl_xor(v, 16));
      v = fmaxf(v, __shfl_xor(v, 32));
      if ((lane >> 4) == 0){
        int g = groupBase + (bm >> 4) + (wm >> 4) + mt;
        pooled[(size_t)g * Nd + n] = f2bf(v + bia);
      }
    }
  }
}

// ---------------- tier fallback (f32) ----------------
__global__ __launch_bounds__(256) void fill_diag(float* __restrict__ out, size_t out_elems){
  size_t i = (size_t)blockIdx.x * 256 + threadIdx.x;
  if (i >= out_elems) return;
  size_t maskStart = (size_t)B_ * M_ * D_ + (size_t)B_ * M_ * 4;
  out[i] = (i >= maskStart) ? 1.0f : 0.0f;
}

extern "C" void kernel_launch(void* const* d_in, const int* in_sizes, int n_in,
                              void* d_out, int out_size, void* d_ws, size_t ws_size,
                              hipStream_t stream){
  (void)in_sizes; (void)n_in;
  const float* coords   = (const float*)d_in[0];
  const float* features = (const float*)d_in[1];
  const float* W0 = (const float*)d_in[2];  const float* b0 = (const float*)d_in[3];
  const float* W1 = (const float*)d_in[4];  const float* b1 = (const float*)d_in[5];
  const float* W2 = (const float*)d_in[6];  const float* b2 = (const float*)d_in[7];
  const float* W3 = (const float*)d_in[8];  const float* b3 = (const float*)d_in[9];
  const float* Wn0 = (const float*)d_in[10]; const float* bn0 = (const float*)d_in[11];
  const float* Wn1 = (const float*)d_in[12]; const float* bn1 = (const float*)d_in[13];
  float* out = (float*)d_out;
  const size_t out_elems = (size_t)out_size;

  char* ws = (char*)d_ws;
  const size_t o_cent = 0;            // 16,384 (FPS order)
  const size_t o_cntS = 16384;        // 16,384 (time order)
  const size_t o_knn  = 32768;        // 65,536 -> 98,304
  const size_t o_Wb   = 131072;       // 4,587,520 bf16 W1t..Wn1t (transposed)
  const size_t o_pool = 4718592;      // 1,572,864 bf16 [1024,768]
  const size_t o_t1   = 6291456;      // 1,572,864
  const size_t o_chunk= 7864320;      // regA (R*1536 B) + regB (R*1024 B)
  const int ROWS = B_ * M_ * K_;      // 16384

  int R = 16384;
  while (R > 128 && o_chunk + (size_t)R * 2560 > ws_size) R >>= 1;
  if (d_ws == nullptr || o_chunk + (size_t)R * 2560 > ws_size){
    fill_diag<<<(int)((out_elems + 255) / 256), 256, 0, stream>>>(out, out_elems);
    return;
  }

  float* cent_fps    = (float*)(ws + o_cent);
  float* cent_sorted = (float*)(ws + o_cntS);
  int*   knn         = (int*)(ws + o_knn);
  u16* Wb   = (u16*)(ws + o_Wb);
  u16* W1t  = Wb;               u16* W2t  = Wb + 131072;
  u16* W3t  = Wb + 524288;      u16* Wn0t = Wb + 1114112;
  u16* Wn1t = Wb + 1703936;
  u16* pooled = (u16*)(ws + o_pool);
  u16* t1     = (u16*)(ws + o_t1);
  u16* regA   = (u16*)(ws + o_chunk);                      // h1 [R,256] then h3 [R,768]
  u16* regB   = (u16*)(ws + o_chunk + (size_t)R * 1536);   // h2 [R,512]

  conv_all<<<560, 256, 0, stream>>>(W1, W2, W3, Wn0, Wn1, Wb);
  fps_block<<<B_, 1024, 0, stream>>>(coords, cent_fps);
  rank_scatter<<<B_, 128, 0, stream>>>(cent_fps, cent_sorted, out, out_elems);
  knn_kernel<<<B_ * M_, KNT, 0, stream>>>(coords, cent_sorted, knn);

  for (int rowBase = 0; rowBase < ROWS; rowBase += R){
    gather_l0<<<R / 32, 256, 0, stream>>>(features, knn, W0, b0, regA, rowBase);
    gemm_bf16<1,0><<<dim3(4, R / 128), 256, 0, stream>>>(regA, W1t, b1, regB, 256, 512);
    gemm_bf16<1,0><<<dim3(6, R / 128), 256, 0, stream>>>(regB, W2t, b2, regA, 512, 768);
    gemm_pool<<<dim3(6, R / 128), 256, 0, stream>>>(regA, W3t, b3, pooled, 768, 768, rowBase >> 4);
  }

  gemm64<1,0><<<dim3(12, (B_ * M_) / 64), 256, 0, stream>>>(pooled, Wn0t, bn0, t1, 768, 768);
  gemm64<0,1><<<dim3(12, (B_ * M_) / 64), 256, 0, stream>>>(t1, Wn1t, bn1, out, 768, 768);
}

// Round 9
// 574.711 us; speedup vs baseline: 1.0080x; 1.0080x over previous
//
#include <hip/hip_runtime.h>

#define B_ 8
#define N_ 16384
#define F_ 6
#define M_ 128
#define K_ 16
#define D_ 768

typedef unsigned short u16;
typedef unsigned int u32;
typedef unsigned long long u64;
typedef __attribute__((ext_vector_type(8))) short short8;
typedef __attribute__((ext_vector_type(4))) float f32x4;
typedef __attribute__((ext_vector_type(2))) float f32x2;

__device__ __forceinline__ u16 f2bf(float f){
  union { float f; u32 i; } v; v.f = f;
  u32 x = v.i;
  u32 r = x + 0x7FFFu + ((x >> 16) & 1u);
  return (u16)(r >> 16);
}

// async 16B global->LDS (dest = wave-uniform base + lane*16)
__device__ __forceinline__ void ld_g2l(const u16* g, u16* l){
  __builtin_amdgcn_global_load_lds((const __attribute__((address_space(1))) u32*)g,
                                   (__attribute__((address_space(3))) u32*)l, 16, 0, 0);
}

// VOLATILE asm 16B load: result cannot be rematerialized from memory by LLVM.
__device__ __forceinline__ f32x4 ld_x4(const float* p){
  f32x4 r;
  asm volatile("global_load_dwordx4 %0, %1, off" : "=v"(r) : "v"(p) : "memory");
  return r;
}

// DPP self-max step: v = max(v, lane-shifted v). Full-rate VALU — no LDS, no lgkmcnt.
template<int CTRL>
__device__ __forceinline__ float dppmax(float v){
  union { float f; int i; } a, r;
  a.f = v;
  r.i = __builtin_amdgcn_update_dpp(a.i, a.i, CTRL, 0xF, 0xF, false);
  return fmaxf(v, r.f);
}

// ---------------- all weights f32 -> bf16 transposed [n][k], ONE kernel ----------------
__global__ __launch_bounds__(256) void conv_all(const float* __restrict__ W1,
                                                const float* __restrict__ W2,
                                                const float* __restrict__ W3,
                                                const float* __restrict__ Wn0,
                                                const float* __restrict__ Wn1,
                                                u16* __restrict__ Wb){
  __shared__ u16 tile[64][65];
  int blk = blockIdx.x;
  const float* W; u16* WT; int K, N, lb;
  if      (blk < 32)  { W = W1;  WT = Wb;           K = 256; N = 512; lb = blk; }
  else if (blk < 128) { W = W2;  WT = Wb + 131072;  K = 512; N = 768; lb = blk - 32; }
  else if (blk < 272) { W = W3;  WT = Wb + 524288;  K = 768; N = 768; lb = blk - 128; }
  else if (blk < 416) { W = Wn0; WT = Wb + 1114112; K = 768; N = 768; lb = blk - 272; }
  else                { W = Wn1; WT = Wb + 1703936; K = 768; N = 768; lb = blk - 416; }
  int tiles_n = N >> 6;
  int tk = lb / tiles_n, tn = lb % tiles_n;
  int k0 = tk << 6, n0 = tn << 6;
  int t = threadIdx.x;
#pragma unroll
  for (int q = 0; q < 16; q++){
    int idx = q * 256 + t;
    int kk = idx >> 6, nn = idx & 63;
    tile[kk][nn] = f2bf(W[(size_t)(k0 + kk) * N + n0 + nn]);
  }
  __syncthreads();
#pragma unroll
  for (int q = 0; q < 16; q++){
    int idx = q * 256 + t;
    int nn = idx >> 6, kk = idx & 63;
    WT[(size_t)(n0 + nn) * K + k0 + kk] = tile[kk][nn];
  }
}

// ---------------- FPS: r8 structure, de-bloated codegen ----------------
// r8 PMC verdict: step loop is ISSUE-bound at ~37 instr/point (should be ~15). Bloat =
// (a) inline-asm v_pk ops forcing v_mov copies around every asm, (b) per-read LDS addr
// arithmetic. Fix: plain C float math (contract off keeps reference rounding), literal-k
// LDS indexing so ds_read folds k*8192 into the offset: immediate. Structure unchanged:
// xy in LDS (interleaved slot = k*1024+t, conflict-free), pzw+md in 48 regs (volatile-
// pinned), DPP wave-argmax + ballot + LDS combine tail (harness-verified in r8).
// Thread t owns CONTIGUOUS points [16t,16t+16) -> lane order == index order; ties resolve
// by lowest lane (ballot) then lowest wave (strict > scan) == jnp.argmax first-max.
// Exact math: d = ((dx*dx + dy*dy) + dz*dz) + dw*dw, md = min(md, d).
#define FPT 16   // points per thread: 16384 / 1024
__global__ __launch_bounds__(1024)
void fps_block(const float* __restrict__ coords, float* __restrict__ cent){
#pragma clang fp contract(off)
  __shared__ f32x2 sxy[N_];          // 128 KB, interleaved slot = k*1024 + t
  __shared__ f32x4 swv4[2][4];       // 16 wave maxima as 4x f32x4 (b128 scan reads)
  __shared__ f32x4 swc[2][16];       // winning candidate coords per wave
  int b = blockIdx.x;
  int t = threadIdx.x;
  int lane = t & 63, wave = t >> 6;
  const float* cb = coords + (size_t)b * N_ * 5;
  const int base = t << 4;                        // first point index owned by this thread
  f32x4 q[FPT];
#pragma unroll
  for (int k = 0; k < FPT; k++)
    q[k] = ld_x4(cb + (size_t)(base + k) * 5 + 1);   // (x,y,z,w), volatile
  asm volatile("s_waitcnt vmcnt(0)" ::: "memory");   // ONE drain for all 16 loads
  __builtin_amdgcn_sched_barrier(0);                 // rule #18: pin uses after the wait
  f32x2 pzw[FPT];
  float md[FPT];
#pragma unroll
  for (int k = 0; k < FPT; k++){
    sxy[k * 1024 + t] = (f32x2){q[k][0], q[k][1]};
    pzw[k] = (f32x2){q[k][2], q[k][3]};
    md[k] = 1e30f;
  }
  float cx = cb[1], cy = cb[2], cz = cb[3], ct = cb[4];
  if (t == 0){
    float* c0 = cent + (size_t)b * M_ * 4;
    c0[0]=cx; c0[1]=cy; c0[2]=cz; c0[3]=ct;
  }
  for (int step = 1; step < M_; step++){
    float bv = -1.0f; int bl = 0;
#pragma unroll
    for (int k = 0; k < FPT; k++){
      f32x2 xy = sxy[k * 1024 + t];                // ds_read_b64, k*8192 -> offset imm
      float dx = xy[0] - cx;
      float dy = xy[1] - cy;
      float dz = pzw[k][0] - cz;
      float dw = pzw[k][1] - ct;
      float s = ((dx*dx + dy*dy) + dz*dz) + dw*dw; // reference rounding order (contract off)
      float m = fminf(s, md[k]);
      md[k] = m;
      if (m > bv){ bv = m; bl = k; }               // ascending-index first-max
    }
    // ---- wave argmax: 6 DPP fmax levels -> lane 63 holds wave max ----
    float r = bv;
    r = dppmax<0x111>(r);        // row_shr:1
    r = dppmax<0x112>(r);        // row_shr:2
    r = dppmax<0x114>(r);        // row_shr:4
    r = dppmax<0x118>(r);        // row_shr:8
    r = dppmax<0x142>(r);        // row_bcast:15
    r = dppmax<0x143>(r);        // row_bcast:31
    union { float f; int i; } rm; rm.f = r;
    union { int i; float f; } wmu; wmu.i = __builtin_amdgcn_readlane(rm.i, 63);
    float wmax = wmu.f;                            // uniform
    u64 wmask = __ballot(bv == wmax);
    int srcL = (int)__ffsll((unsigned long long)wmask) - 1;  // lowest lane = lowest index
    // select winner's zw by compile-time-indexed cndmask chain (rule #20: no dyn reg index)
    f32x2 zwsel = pzw[0];
#pragma unroll
    for (int k = 1; k < FPT; k++) zwsel = (bl == k) ? pzw[k] : zwsel;
    int par = step & 1;
    if (lane == srcL){
      f32x2 xyw = sxy[bl * 1024 + t];              // winner's xy from own LDS slot
      ((float*)&swv4[par])[wave] = bv;
      swc[par][wave] = (f32x4){xyw[0], xyw[1], zwsel[0], zwsel[1]};
    }
    __syncthreads();                               // only barrier per step
    // ---- block combine: 4x b128 broadcast reads + strict-greater scan over 16 waves ----
    float fv; int fw = 0;
    {
      f32x4 v0 = swv4[par][0], v1 = swv4[par][1], v2 = swv4[par][2], v3 = swv4[par][3];
      fv = v0[0];
#pragma unroll
      for (int j = 1; j < 4; j++) if (v0[j] > fv){ fv = v0[j]; fw = j; }
#pragma unroll
      for (int j = 0; j < 4; j++) if (v1[j] > fv){ fv = v1[j]; fw = 4 + j; }
#pragma unroll
      for (int j = 0; j < 4; j++) if (v2[j] > fv){ fv = v2[j]; fw = 8 + j; }
#pragma unroll
      for (int j = 0; j < 4; j++) if (v3[j] > fv){ fv = v3[j]; fw = 12 + j; }
    }
    f32x4 wc = swc[par][fw];                       // broadcast b128 read
    cx = wc[0]; cy = wc[1]; cz = wc[2]; ct = wc[3];
    if (t == 0){
      float* cr = cent + ((size_t)b * M_ + step) * 4;
      cr[0]=cx; cr[1]=cy; cr[2]=cz; cr[3]=ct;
    }
  }
}

// ---------------- stable rank by centroid time; relabel early; f32 outputs ----------------
__global__ __launch_bounds__(128) void rank_scatter(const float* __restrict__ cent_fps,
                                                    float* __restrict__ cent_sorted,
                                                    float* __restrict__ out,
                                                    size_t out_elems){
  int b = blockIdx.x, m = threadIdx.x;
  __shared__ float tt[M_];
  const float* row = cent_fps + ((size_t)b * M_ + m) * 4;
  float x=row[0], y=row[1], z=row[2], w=row[3];
  tt[m] = w;
  __syncthreads();
  int rank = 0;
  for (int j = 0; j < M_; j++){
    float tj = tt[j];
    if (tj < w || (tj == w && j < m)) rank++;       // stable argsort semantics
  }
  float* dst = cent_sorted + ((size_t)b * M_ + rank) * 4;
  dst[0]=x; dst[1]=y; dst[2]=z; dst[3]=w;
  size_t co = (size_t)B_ * M_ * D_ + ((size_t)b * M_ + rank) * 4;
  if (co + 3 < out_elems){
    out[co+0]=x; out[co+1]=y; out[co+2]=z; out[co+3]=w;
  }
  size_t mo = (size_t)B_ * M_ * D_ + (size_t)B_ * M_ * 4 + (size_t)b * M_ + m;
  if (mo < out_elems) out[mo] = 1.0f;              // mask = True -> 1.0f
}

// ---------------- kNN: f32, np op order, stable-min extraction ----------------
#define KNT 512
#define KPT 32
__global__ __launch_bounds__(512) void knn_kernel(const float* __restrict__ coords,
                                                  const float* __restrict__ cent,
                                                  int* __restrict__ knn){
#pragma clang fp contract(off)
  int cm = blockIdx.x;
  int b = cm >> 7;
  const float* cb = coords + (size_t)b * N_ * 5;
  int t = threadIdx.x;
  float cx=cent[cm*4+0], cy=cent[cm*4+1], cz=cent[cm*4+2], ct=cent[cm*4+3];
  float dist[KPT];
#pragma unroll
  for (int j = 0; j < KPT; j++){
    size_t i = t + j * KNT;
    float dx=cb[i*5+1]-cx, dy=cb[i*5+2]-cy, dz=cb[i*5+3]-cz, dw=cb[i*5+4]-ct;
    float d = ((dx*dx + dy*dy) + dz*dz) + dw*dw;
    dist[j] = sqrtf(d);                            // IEEE f32 sqrt = np.sqrt(f32)
  }
  __shared__ float s_wv[8];
  __shared__ int s_wi[8];
  __shared__ int s_bi;
  for (int r = 0; r < K_; r++){
    float bv = 3e38f; int bi = 1 << 30;
#pragma unroll
    for (int j = 0; j < KPT; j++){
      int i = t + j * KNT;
      float v = dist[j];
      if (v < bv){ bv = v; bi = i; }               // first-min kept
    }
#pragma unroll
    for (int off = 32; off > 0; off >>= 1){
      float ov = __shfl_down(bv, off);
      int oi = __shfl_down(bi, off);
      if (ov < bv || (ov == bv && oi < bi)){ bv = ov; bi = oi; }
    }
    if ((t & 63) == 0){ s_wv[t >> 6] = bv; s_wi[t >> 6] = bi; }
    __syncthreads();
    if (t == 0){
      float fv = s_wv[0]; int fi = s_wi[0];
      for (int w = 1; w < 8; w++){
        float wv = s_wv[w]; int wi = s_wi[w];
        if (wv < fv || (wv == fv && wi < fi)){ fv = wv; fi = wi; }
      }
      s_bi = fi;
      knn[(size_t)cm * K_ + r] = fi & (N_ - 1);
    }
    __syncthreads();
    int wi = s_bi;
#pragma unroll
    for (int j = 0; j < KPT; j++){
      if (t + j * KNT == wi) dist[j] = 3e38f;
    }
  }
}

// ---------------- gather + layer0: 32 rows/block, W0/b0/features LDS-staged ----------------
__global__ __launch_bounds__(256) void gather_l0(const float* __restrict__ feat,
                                                 const int* __restrict__ knn,
                                                 const float* __restrict__ W0,
                                                 const float* __restrict__ b0,
                                                 u16* __restrict__ h1,
                                                 int rowBase){
  __shared__ float sW[F_][256];
  __shared__ float sb[256];
  __shared__ float sfa[32][F_];
  int t = threadIdx.x;
#pragma unroll
  for (int k = 0; k < F_; k++) sW[k][t] = W0[k * 256 + t];
  sb[t] = b0[t];
  if (t < 32 * F_){
    int r = t / F_, k = t % F_;
    int grow = rowBase + blockIdx.x * 32 + r;
    int bb = grow >> 11;                          // /(M*K)=2048
    int idx = knn[grow] & (N_ - 1);
    sfa[r][k] = feat[((size_t)bb * N_ + idx) * F_ + k];
  }
  __syncthreads();
#pragma unroll 4
  for (int r = 0; r < 32; r++){
    float acc = sb[t];
#pragma unroll
    for (int k = 0; k < F_; k++) acc = fmaf(sfa[r][k], sW[k][t], acc);
    int lrow = blockIdx.x * 32 + r;
    h1[(size_t)lrow * 256 + t] = f2bf(fmaxf(acc, 0.0f));
  }
}

// ---------------- bf16 MFMA GEMM (128x128), async global->LDS staging ----------------
// Unpadded [128][32] rows (64B): dest = wave-uniform base + lane*16 (m97 layout).
template<int RELU, int OUTF32>
__global__ __launch_bounds__(256) void gemm_bf16(const u16* __restrict__ A,
                                                 const u16* __restrict__ WT,
                                                 const float* __restrict__ bias,
                                                 void* __restrict__ Cv,
                                                 int Kd, int Nd){
  __shared__ u16 As[128][32];
  __shared__ u16 Bs[128][32];
  const int t = threadIdx.x;
  const int bm = blockIdx.y << 7;
  const int bn = blockIdx.x << 7;
  const int wave = t >> 6;
  const int lane = t & 63;
  const int wm = (wave & 1) << 6;
  const int wn = (wave >> 1) << 6;
  const int lm = lane & 15;
  const int lk = (lane >> 4) << 3;
  u16* AsF = &As[0][0];
  u16* BsF = &Bs[0][0];
  const int wbase = wave << 6;               // t - lane
  f32x4 acc[4][4] = {};
  for (int k0 = 0; k0 < Kd; k0 += 32){
#pragma unroll
    for (int it = 0; it < 2; it++){
      int slot = t + (it << 8);
      int r = slot >> 2;
      int c = (slot & 3) << 3;
      int dst = (wbase + (it << 8)) << 3;    // u16 elements; +lane*16B by HW
      ld_g2l(A  + (size_t)(bm + r) * Kd + k0 + c, AsF + dst);
      ld_g2l(WT + (size_t)(bn + r) * Kd + k0 + c, BsF + dst);
    }
    __syncthreads();
    short8 af[4], bfr[4];
#pragma unroll
    for (int mt = 0; mt < 4; mt++) af[mt] = *(const short8*)&As[wm + (mt << 4) + lm][lk];
#pragma unroll
    for (int nt = 0; nt < 4; nt++) bfr[nt] = *(const short8*)&Bs[wn + (nt << 4) + lm][lk];
#pragma unroll
    for (int mt = 0; mt < 4; mt++)
#pragma unroll
      for (int nt = 0; nt < 4; nt++)
        acc[mt][nt] = __builtin_amdgcn_mfma_f32_16x16x32_bf16(af[mt], bfr[nt], acc[mt][nt], 0, 0, 0);
    __syncthreads();
  }
#pragma unroll
  for (int nt = 0; nt < 4; nt++){
    int n = bn + wn + (nt << 4) + lm;
    float bia = bias[n];
#pragma unroll
    for (int mt = 0; mt < 4; mt++){
#pragma unroll
      for (int r2 = 0; r2 < 4; r2++){
        int m = bm + wm + (mt << 4) + ((lane >> 4) << 2) + r2;
        float v = acc[mt][nt][r2] + bia;
        if (RELU) v = fmaxf(v, 0.0f);
        if (OUTF32) ((float*)Cv)[(size_t)m * Nd + n] = v;
        else        ((u16*)Cv)[(size_t)m * Nd + n] = f2bf(v);
      }
    }
  }
}

// ---------------- bf16 MFMA GEMM (64x64), async staging, token GEMMs ----------------
template<int RELU, int OUTF32>
__global__ __launch_bounds__(256) void gemm64(const u16* __restrict__ A,
                                              const u16* __restrict__ WT,
                                              const float* __restrict__ bias,
                                              void* __restrict__ Cv,
                                              int Kd, int Nd){
  __shared__ u16 As[64][32];
  __shared__ u16 Bs[64][32];
  const int t = threadIdx.x;
  const int bm = blockIdx.y << 6;
  const int bn = blockIdx.x << 6;
  const int wave = t >> 6;
  const int lane = t & 63;
  const int wm = (wave & 1) << 5;
  const int wn = (wave >> 1) << 5;
  const int lm = lane & 15;
  const int lk = (lane >> 4) << 3;
  u16* AsF = &As[0][0];
  u16* BsF = &Bs[0][0];
  const int wbase = wave << 6;
  f32x4 acc[2][2] = {};
  for (int k0 = 0; k0 < Kd; k0 += 32){
    {
      int r = t >> 2;
      int c = (t & 3) << 3;
      int dst = wbase << 3;
      ld_g2l(A  + (size_t)(bm + r) * Kd + k0 + c, AsF + dst);
      ld_g2l(WT + (size_t)(bn + r) * Kd + k0 + c, BsF + dst);
    }
    __syncthreads();
    short8 af[2], bfr[2];
#pragma unroll
    for (int mt = 0; mt < 2; mt++) af[mt] = *(const short8*)&As[wm + (mt << 4) + lm][lk];
#pragma unroll
    for (int nt = 0; nt < 2; nt++) bfr[nt] = *(const short8*)&Bs[wn + (nt << 4) + lm][lk];
#pragma unroll
    for (int mt = 0; mt < 2; mt++)
#pragma unroll
      for (int nt = 0; nt < 2; nt++)
        acc[mt][nt] = __builtin_amdgcn_mfma_f32_16x16x32_bf16(af[mt], bfr[nt], acc[mt][nt], 0, 0, 0);
    __syncthreads();
  }
#pragma unroll
  for (int nt = 0; nt < 2; nt++){
    int n = bn + wn + (nt << 4) + lm;
    float bia = bias[n];
#pragma unroll
    for (int mt = 0; mt < 2; mt++){
#pragma unroll
      for (int r2 = 0; r2 < 4; r2++){
        int m = bm + wm + (mt << 4) + ((lane >> 4) << 2) + r2;
        float v = acc[mt][nt][r2] + bia;
        if (RELU) v = fmaxf(v, 0.0f);
        if (OUTF32) ((float*)Cv)[(size_t)m * Nd + n] = v;
        else        ((u16*)Cv)[(size_t)m * Nd + n] = f2bf(v);
      }
    }
  }
}

// ---------------- GEMM + fused max-pool (128x128), async staging ----------------
__global__ __launch_bounds__(256) void gemm_pool(const u16* __restrict__ A,
                                                 const u16* __restrict__ WT,
                                                 const float* __restrict__ bias,
                                                 u16* __restrict__ pooled,
                                                 int Kd, int Nd, int groupBase){
  __shared__ u16 As[128][32];
  __shared__ u16 Bs[128][32];
  const int t = threadIdx.x;
  const int bm = blockIdx.y << 7;
  const int bn = blockIdx.x << 7;
  const int wave = t >> 6;
  const int lane = t & 63;
  const int wm = (wave & 1) << 6;
  const int wn = (wave >> 1) << 6;
  const int lm = lane & 15;
  const int lk = (lane >> 4) << 3;
  u16* AsF = &As[0][0];
  u16* BsF = &Bs[0][0];
  const int wbase = wave << 6;
  f32x4 acc[4][4] = {};
  for (int k0 = 0; k0 < Kd; k0 += 32){
#pragma unroll
    for (int it = 0; it < 2; it++){
      int slot = t + (it << 8);
      int r = slot >> 2;
      int c = (slot & 3) << 3;
      int dst = (wbase + (it << 8)) << 3;
      ld_g2l(A  + (size_t)(bm + r) * Kd + k0 + c, AsF + dst);
      ld_g2l(WT + (size_t)(bn + r) * Kd + k0 + c, BsF + dst);
    }
    __syncthreads();
    short8 af[4], bfr[4];
#pragma unroll
    for (int mt = 0; mt < 4; mt++) af[mt] = *(const short8*)&As[wm + (mt << 4) + lm][lk];
#pragma unroll
    for (int nt = 0; nt < 4; nt++) bfr[nt] = *(const short8*)&Bs[wn + (nt << 4) + lm][lk];
#pragma unroll
    for (int mt = 0; mt < 4; mt++)
#pragma unroll
      for (int nt = 0; nt < 4; nt++)
        acc[mt][nt] = __builtin_amdgcn_mfma_f32_16x16x32_bf16(af[mt], bfr[nt], acc[mt][nt], 0, 0, 0);
    __syncthreads();
  }
  // each (mt) tile's 16 rows are exactly one pooling group
#pragma unroll
  for (int nt = 0; nt < 4; nt++){
    int n = bn + wn + (nt << 4) + lm;
    float bia = bias[n];
#pragma unroll
    for (int mt = 0; mt < 4; mt++){
      f32x4 a = acc[mt][nt];
      float v = fmaxf(fmaxf(a[0], a[1]), fmaxf(a[2], a[3]));
      v = fmaxf(v, __shfl_xor(v, 16));
      v = fmaxf(v, __shfl_xor(v, 32));
      if ((lane >> 4) == 0){
        int g = groupBase + (bm >> 4) + (wm >> 4) + mt;
        pooled[(size_t)g * Nd + n] = f2bf(v + bia);
      }
    }
  }
}

// ---------------- tier fallback (f32) ----------------
__global__ __launch_bounds__(256) void fill_diag(float* __restrict__ out, size_t out_elems){
  size_t i = (size_t)blockIdx.x * 256 + threadIdx.x;
  if (i >= out_elems) return;
  size_t maskStart = (size_t)B_ * M_ * D_ + (size_t)B_ * M_ * 4;
  out[i] = (i >= maskStart) ? 1.0f : 0.0f;
}

extern "C" void kernel_launch(void* const* d_in, const int* in_sizes, int n_in,
                              void* d_out, int out_size, void* d_ws, size_t ws_size,
                              hipStream_t stream){
  (void)in_sizes; (void)n_in;
  const float* coords   = (const float*)d_in[0];
  const float* features = (const float*)d_in[1];
  const float* W0 = (const float*)d_in[2];  const float* b0 = (const float*)d_in[3];
  const float* W1 = (const float*)d_in[4];  const float* b1 = (const float*)d_in[5];
  const float* W2 = (const float*)d_in[6];  const float* b2 = (const float*)d_in[7];
  const float* W3 = (const float*)d_in[8];  const float* b3 = (const float*)d_in[9];
  const float* Wn0 = (const float*)d_in[10]; const float* bn0 = (const float*)d_in[11];
  const float* Wn1 = (const float*)d_in[12]; const float* bn1 = (const float*)d_in[13];
  float* out = (float*)d_out;
  const size_t out_elems = (size_t)out_size;

  char* ws = (char*)d_ws;
  const size_t o_cent = 0;            // 16,384 (FPS order)
  const size_t o_cntS = 16384;        // 16,384 (time order)
  const size_t o_knn  = 32768;        // 65,536 -> 98,304
  const size_t o_Wb   = 131072;       // 4,587,520 bf16 W1t..Wn1t (transposed)
  const size_t o_pool = 4718592;      // 1,572,864 bf16 [1024,768]
  const size_t o_t1   = 6291456;      // 1,572,864
  const size_t o_chunk= 7864320;      // regA (R*1536 B) + regB (R*1024 B)
  const int ROWS = B_ * M_ * K_;      // 16384

  int R = 16384;
  while (R > 128 && o_chunk + (size_t)R * 2560 > ws_size) R >>= 1;
  if (d_ws == nullptr || o_chunk + (size_t)R * 2560 > ws_size){
    fill_diag<<<(int)((out_elems + 255) / 256), 256, 0, stream>>>(out, out_elems);
    return;
  }

  float* cent_fps    = (float*)(ws + o_cent);
  float* cent_sorted = (float*)(ws + o_cntS);
  int*   knn         = (int*)(ws + o_knn);
  u16* Wb   = (u16*)(ws + o_Wb);
  u16* W1t  = Wb;               u16* W2t  = Wb + 131072;
  u16* W3t  = Wb + 524288;      u16* Wn0t = Wb + 1114112;
  u16* Wn1t = Wb + 1703936;
  u16* pooled = (u16*)(ws + o_pool);
  u16* t1     = (u16*)(ws + o_t1);
  u16* regA   = (u16*)(ws + o_chunk);                      // h1 [R,256] then h3 [R,768]
  u16* regB   = (u16*)(ws + o_chunk + (size_t)R * 1536);   // h2 [R,512]

  conv_all<<<560, 256, 0, stream>>>(W1, W2, W3, Wn0, Wn1, Wb);
  fps_block<<<B_, 1024, 0, stream>>>(coords, cent_fps);
  rank_scatter<<<B_, 128, 0, stream>>>(cent_fps, cent_sorted, out, out_elems);
  knn_kernel<<<B_ * M_, KNT, 0, stream>>>(coords, cent_sorted, knn);

  for (int rowBase = 0; rowBase < ROWS; rowBase += R){
    gather_l0<<<R / 32, 256, 0, stream>>>(features, knn, W0, b0, regA, rowBase);
    gemm_bf16<1,0><<<dim3(4, R / 128), 256, 0, stream>>>(regA, W1t, b1, regB, 256, 512);
    gemm_bf16<1,0><<<dim3(6, R / 128), 256, 0, stream>>>(regB, W2t, b2, regA, 512, 768);
    gemm_pool<<<dim3(6, R / 128), 256, 0, stream>>>(regA, W3t, b3, pooled, 768, 768, rowBase >> 4);
  }

  gemm64<1,0><<<dim3(12, (B_ * M_) / 64), 256, 0, stream>>>(pooled, Wn0t, bn0, t1, 768, 768);
  gemm64<0,1><<<dim3(12, (B_ * M_) / 64), 256, 0, stream>>>(t1, Wn1t, bn1, out, 768, 768);
}

// Round 10
// 514.817 us; speedup vs baseline: 1.1252x; 1.1163x over previous
//
#include <hip/hip_runtime.h>

#define B_ 8
#define N_ 16384
#define F_ 6
#define M_ 128
#define K_ 16
#define D_ 768

typedef unsigned short u16;
typedef unsigned int u32;
typedef unsigned long long u64;
typedef __attribute__((ext_vector_type(8))) short short8;
typedef __attribute__((ext_vector_type(4))) float f32x4;
typedef __attribute__((ext_vector_type(2))) float f32x2;

__device__ __forceinline__ u16 f2bf(float f){
  union { float f; u32 i; } v; v.f = f;
  u32 x = v.i;
  u32 r = x + 0x7FFFu + ((x >> 16) & 1u);
  return (u16)(r >> 16);
}

// async 16B global->LDS (dest = wave-uniform base + lane*16)
__device__ __forceinline__ void ld_g2l(const u16* g, u16* l){
  __builtin_amdgcn_global_load_lds((const __attribute__((address_space(1))) u32*)g,
                                   (__attribute__((address_space(3))) u32*)l, 16, 0, 0);
}

// VOLATILE asm 16B load: result cannot be rematerialized from memory by LLVM.
__device__ __forceinline__ f32x4 ld_x4(const float* p){
  f32x4 r;
  asm volatile("global_load_dwordx4 %0, %1, off" : "=v"(r) : "v"(p) : "memory");
  return r;
}

// DPP self-max step: v = max(v, lane-shifted v). Full-rate VALU — no LDS, no lgkmcnt.
template<int CTRL>
__device__ __forceinline__ float dppmax(float v){
  union { float f; int i; } a, r;
  a.f = v;
  r.i = __builtin_amdgcn_update_dpp(a.i, a.i, CTRL, 0xF, 0xF, false);
  return fmaxf(v, r.f);
}

// ---------------- all weights f32 -> bf16 transposed [n][k], ONE kernel ----------------
__global__ __launch_bounds__(256) void conv_all(const float* __restrict__ W1,
                                                const float* __restrict__ W2,
                                                const float* __restrict__ W3,
                                                const float* __restrict__ Wn0,
                                                const float* __restrict__ Wn1,
                                                u16* __restrict__ Wb){
  __shared__ u16 tile[64][65];
  int blk = blockIdx.x;
  const float* W; u16* WT; int K, N, lb;
  if      (blk < 32)  { W = W1;  WT = Wb;           K = 256; N = 512; lb = blk; }
  else if (blk < 128) { W = W2;  WT = Wb + 131072;  K = 512; N = 768; lb = blk - 32; }
  else if (blk < 272) { W = W3;  WT = Wb + 524288;  K = 768; N = 768; lb = blk - 128; }
  else if (blk < 416) { W = Wn0; WT = Wb + 1114112; K = 768; N = 768; lb = blk - 272; }
  else                { W = Wn1; WT = Wb + 1703936; K = 768; N = 768; lb = blk - 416; }
  int tiles_n = N >> 6;
  int tk = lb / tiles_n, tn = lb % tiles_n;
  int k0 = tk << 6, n0 = tn << 6;
  int t = threadIdx.x;
#pragma unroll
  for (int q = 0; q < 16; q++){
    int idx = q * 256 + t;
    int kk = idx >> 6, nn = idx & 63;
    tile[kk][nn] = f2bf(W[(size_t)(k0 + kk) * N + n0 + nn]);
  }
  __syncthreads();
#pragma unroll
  for (int q = 0; q < 16; q++){
    int idx = q * 256 + t;
    int nn = idx >> 6, kk = idx & 63;
    WT[(size_t)(n0 + nn) * K + k0 + kk] = tile[kk][nn];
  }
}

// ---------------- FPS v10: 512 thr (cheap 8-wave tail) + xy-LDS / zw+md-regs ----------------
// r7 lesson: 512-thr tail is cheap but spilled state re-reads 256KB/step from L2 (4700cy).
// r8/r9 lesson: LDS-xy removes re-reads but 16-wave tail+issue costs 6150cy.
// v10 = both fixes: 8 waves, xy in LDS (slot k*512+t, self-owned, conflict-free),
// pzw[32] volatile-pinned (64 regs, non-rematerializable) + md[32] (32 regs).
// LDS 131KB -> 1 block/CU -> 2 waves/SIMD -> 256-VGPR budget: no squeeze incentive.
// Thread t owns CONTIGUOUS points [32t,32t+32) -> lane order == index order; ties resolve
// by lowest lane (ballot), then lowest wave (strict > scan) == jnp.argmax first-max.
// Exact math: d = ((dx*dx + dy*dy) + dz*dz) + dw*dw (contract off), md = min(md, d).
#define FPT 32   // points per thread: 16384 / 512
__global__ __launch_bounds__(512)
void fps_block(const float* __restrict__ coords, float* __restrict__ cent){
#pragma clang fp contract(off)
  __shared__ f32x2 sxy[N_];          // 128 KB, slot = k*512 + t (self-owned)
  __shared__ float swv[2][8];
  __shared__ int   swi[2][8];
  int b = blockIdx.x;
  int t = threadIdx.x;
  int lane = t & 63, wave = t >> 6;
  const float* cb = coords + (size_t)b * N_ * 5;
  const int base = t << 5;                        // first point index owned by this thread
  f32x2 pzw[FPT];
  float md[FPT];
  // init in 4 groups of 8: peak transient regs ~140 (under the 256 budget), one drain/group
#pragma unroll
  for (int g = 0; g < 4; g++){
    f32x4 qg[8];
#pragma unroll
    for (int k2 = 0; k2 < 8; k2++)
      qg[k2] = ld_x4(cb + (size_t)(base + g * 8 + k2) * 5 + 1);   // (x,y,z,w), volatile
    asm volatile("s_waitcnt vmcnt(0)" ::: "memory");
    __builtin_amdgcn_sched_barrier(0);            // rule #18: pin uses after the wait
#pragma unroll
    for (int k2 = 0; k2 < 8; k2++){
      int k = g * 8 + k2;
      sxy[k * 512 + t] = (f32x2){qg[k2][0], qg[k2][1]};
      pzw[k] = (f32x2){qg[k2][2], qg[k2][3]};
      md[k] = 1e30f;
    }
  }
  float cx = cb[1], cy = cb[2], cz = cb[3], ct = cb[4];
  if (t == 0){
    float* c0 = cent + (size_t)b * M_ * 4;
    c0[0]=cx; c0[1]=cy; c0[2]=cz; c0[3]=ct;
  }
  for (int step = 1; step < M_; step++){
    float bv = -1.0f; int bl = 0;
#pragma unroll
    for (int k = 0; k < FPT; k++){
      f32x2 xy = sxy[k * 512 + t];               // ds_read_b64, self-owned slot
      float dx = xy[0] - cx;
      float dy = xy[1] - cy;
      float dz = pzw[k][0] - cz;
      float dw = pzw[k][1] - ct;
      float s = ((dx*dx + dy*dy) + dz*dz) + dw*dw; // reference rounding order (contract off)
      float m = fminf(s, md[k]);
      md[k] = m;
      if (m > bv){ bv = m; bl = k; }             // ascending-index first-max
    }
    int bi = base + bl;                          // global point index
    // ---- wave argmax: 6 DPP fmax levels -> lane 63 holds wave max ----
    float r = bv;
    r = dppmax<0x111>(r);        // row_shr:1
    r = dppmax<0x112>(r);        // row_shr:2
    r = dppmax<0x114>(r);        // row_shr:4
    r = dppmax<0x118>(r);        // row_shr:8
    r = dppmax<0x142>(r);        // row_bcast:15
    r = dppmax<0x143>(r);        // row_bcast:31
    union { float f; int i; } rm; rm.f = r;
    union { int i; float f; } wmu; wmu.i = __builtin_amdgcn_readlane(rm.i, 63);
    float wmax = wmu.f;                          // uniform (SGPR)
    u64 wmask = __ballot(bv == wmax);
    int srcL = (int)__ffsll((unsigned long long)wmask) - 1;  // lowest lane = lowest index
    int wbi = __builtin_amdgcn_readlane(bi, srcL);           // uniform winner of this wave
    int par = step & 1;
    if (lane == 0){ swv[par][wave] = wmax; swi[par][wave] = wbi; }
    __syncthreads();                             // only barrier per step
    // ---- block combine: broadcast LDS reads + uniform strict-greater scan over 8 waves ----
    float fv = swv[par][0]; int fi = swi[par][0];
#pragma unroll
    for (int w = 1; w < 8; w++){
      float v = swv[par][w];
      int  iw = swi[par][w];
      if (v > fv){ fv = v; fi = iw; }            // strict > keeps lowest wave (= lowest index)
    }
    int widx = __builtin_amdgcn_readfirstlane(fi);
    size_t wb = (size_t)widx * 5;
    cx = cb[wb+1]; cy = cb[wb+2]; cz = cb[wb+3]; ct = cb[wb+4];  // L1-broadcast, same addr
    if (t == 0){
      float* cr = cent + ((size_t)b * M_ + step) * 4;
      cr[0]=cx; cr[1]=cy; cr[2]=cz; cr[3]=ct;
    }
  }
}

// ---------------- stable rank by centroid time; relabel early; f32 outputs ----------------
__global__ __launch_bounds__(128) void rank_scatter(const float* __restrict__ cent_fps,
                                                    float* __restrict__ cent_sorted,
                                                    float* __restrict__ out,
                                                    size_t out_elems){
  int b = blockIdx.x, m = threadIdx.x;
  __shared__ float tt[M_];
  const float* row = cent_fps + ((size_t)b * M_ + m) * 4;
  float x=row[0], y=row[1], z=row[2], w=row[3];
  tt[m] = w;
  __syncthreads();
  int rank = 0;
  for (int j = 0; j < M_; j++){
    float tj = tt[j];
    if (tj < w || (tj == w && j < m)) rank++;       // stable argsort semantics
  }
  float* dst = cent_sorted + ((size_t)b * M_ + rank) * 4;
  dst[0]=x; dst[1]=y; dst[2]=z; dst[3]=w;
  size_t co = (size_t)B_ * M_ * D_ + ((size_t)b * M_ + rank) * 4;
  if (co + 3 < out_elems){
    out[co+0]=x; out[co+1]=y; out[co+2]=z; out[co+3]=w;
  }
  size_t mo = (size_t)B_ * M_ * D_ + (size_t)B_ * M_ * 4 + (size_t)b * M_ + m;
  if (mo < out_elems) out[mo] = 1.0f;              // mask = True -> 1.0f
}

// ---------------- kNN: f32, np op order, stable-min extraction ----------------
#define KNT 512
#define KPT 32
__global__ __launch_bounds__(512) void knn_kernel(const float* __restrict__ coords,
                                                  const float* __restrict__ cent,
                                                  int* __restrict__ knn){
#pragma clang fp contract(off)
  int cm = blockIdx.x;
  int b = cm >> 7;
  const float* cb = coords + (size_t)b * N_ * 5;
  int t = threadIdx.x;
  float cx=cent[cm*4+0], cy=cent[cm*4+1], cz=cent[cm*4+2], ct=cent[cm*4+3];
  float dist[KPT];
#pragma unroll
  for (int j = 0; j < KPT; j++){
    size_t i = t + j * KNT;
    float dx=cb[i*5+1]-cx, dy=cb[i*5+2]-cy, dz=cb[i*5+3]-cz, dw=cb[i*5+4]-ct;
    float d = ((dx*dx + dy*dy) + dz*dz) + dw*dw;
    dist[j] = sqrtf(d);                            // IEEE f32 sqrt = np.sqrt(f32)
  }
  __shared__ float s_wv[8];
  __shared__ int s_wi[8];
  __shared__ int s_bi;
  for (int r = 0; r < K_; r++){
    float bv = 3e38f; int bi = 1 << 30;
#pragma unroll
    for (int j = 0; j < KPT; j++){
      int i = t + j * KNT;
      float v = dist[j];
      if (v < bv){ bv = v; bi = i; }               // first-min kept
    }
#pragma unroll
    for (int off = 32; off > 0; off >>= 1){
      float ov = __shfl_down(bv, off);
      int oi = __shfl_down(bi, off);
      if (ov < bv || (ov == bv && oi < bi)){ bv = ov; bi = oi; }
    }
    if ((t & 63) == 0){ s_wv[t >> 6] = bv; s_wi[t >> 6] = bi; }
    __syncthreads();
    if (t == 0){
      float fv = s_wv[0]; int fi = s_wi[0];
      for (int w = 1; w < 8; w++){
        float wv = s_wv[w]; int wi = s_wi[w];
        if (wv < fv || (wv == fv && wi < fi)){ fv = wv; fi = wi; }
      }
      s_bi = fi;
      knn[(size_t)cm * K_ + r] = fi & (N_ - 1);
    }
    __syncthreads();
    int wi = s_bi;
#pragma unroll
    for (int j = 0; j < KPT; j++){
      if (t + j * KNT == wi) dist[j] = 3e38f;
    }
  }
}

// ---------------- gather + layer0: 32 rows/block, W0/b0/features LDS-staged ----------------
__global__ __launch_bounds__(256) void gather_l0(const float* __restrict__ feat,
                                                 const int* __restrict__ knn,
                                                 const float* __restrict__ W0,
                                                 const float* __restrict__ b0,
                                                 u16* __restrict__ h1,
                                                 int rowBase){
  __shared__ float sW[F_][256];
  __shared__ float sb[256];
  __shared__ float sfa[32][F_];
  int t = threadIdx.x;
#pragma unroll
  for (int k = 0; k < F_; k++) sW[k][t] = W0[k * 256 + t];
  sb[t] = b0[t];
  if (t < 32 * F_){
    int r = t / F_, k = t % F_;
    int grow = rowBase + blockIdx.x * 32 + r;
    int bb = grow >> 11;                          // /(M*K)=2048
    int idx = knn[grow] & (N_ - 1);
    sfa[r][k] = feat[((size_t)bb * N_ + idx) * F_ + k];
  }
  __syncthreads();
#pragma unroll 4
  for (int r = 0; r < 32; r++){
    float acc = sb[t];
#pragma unroll
    for (int k = 0; k < F_; k++) acc = fmaf(sfa[r][k], sW[k][t], acc);
    int lrow = blockIdx.x * 32 + r;
    h1[(size_t)lrow * 256 + t] = f2bf(fmaxf(acc, 0.0f));
  }
}

// ---------------- bf16 MFMA GEMM (128x128), async global->LDS staging ----------------
// Unpadded [128][32] rows (64B): dest = wave-uniform base + lane*16 (m97 layout).
template<int RELU, int OUTF32>
__global__ __launch_bounds__(256) void gemm_bf16(const u16* __restrict__ A,
                                                 const u16* __restrict__ WT,
                                                 const float* __restrict__ bias,
                                                 void* __restrict__ Cv,
                                                 int Kd, int Nd){
  __shared__ u16 As[128][32];
  __shared__ u16 Bs[128][32];
  const int t = threadIdx.x;
  const int bm = blockIdx.y << 7;
  const int bn = blockIdx.x << 7;
  const int wave = t >> 6;
  const int lane = t & 63;
  const int wm = (wave & 1) << 6;
  const int wn = (wave >> 1) << 6;
  const int lm = lane & 15;
  const int lk = (lane >> 4) << 3;
  u16* AsF = &As[0][0];
  u16* BsF = &Bs[0][0];
  const int wbase = wave << 6;               // t - lane
  f32x4 acc[4][4] = {};
  for (int k0 = 0; k0 < Kd; k0 += 32){
#pragma unroll
    for (int it = 0; it < 2; it++){
      int slot = t + (it << 8);
      int r = slot >> 2;
      int c = (slot & 3) << 3;
      int dst = (wbase + (it << 8)) << 3;    // u16 elements; +lane*16B by HW
      ld_g2l(A  + (size_t)(bm + r) * Kd + k0 + c, AsF + dst);
      ld_g2l(WT + (size_t)(bn + r) * Kd + k0 + c, BsF + dst);
    }
    __syncthreads();
    short8 af[4], bfr[4];
#pragma unroll
    for (int mt = 0; mt < 4; mt++) af[mt] = *(const short8*)&As[wm + (mt << 4) + lm][lk];
#pragma unroll
    for (int nt = 0; nt < 4; nt++) bfr[nt] = *(const short8*)&Bs[wn + (nt << 4) + lm][lk];
#pragma unroll
    for (int mt = 0; mt < 4; mt++)
#pragma unroll
      for (int nt = 0; nt < 4; nt++)
        acc[mt][nt] = __builtin_amdgcn_mfma_f32_16x16x32_bf16(af[mt], bfr[nt], acc[mt][nt], 0, 0, 0);
    __syncthreads();
  }
#pragma unroll
  for (int nt = 0; nt < 4; nt++){
    int n = bn + wn + (nt << 4) + lm;
    float bia = bias[n];
#pragma unroll
    for (int mt = 0; mt < 4; mt++){
#pragma unroll
      for (int r2 = 0; r2 < 4; r2++){
        int m = bm + wm + (mt << 4) + ((lane >> 4) << 2) + r2;
        float v = acc[mt][nt][r2] + bia;
        if (RELU) v = fmaxf(v, 0.0f);
        if (OUTF32) ((float*)Cv)[(size_t)m * Nd + n] = v;
        else        ((u16*)Cv)[(size_t)m * Nd + n] = f2bf(v);
      }
    }
  }
}

// ---------------- bf16 MFMA GEMM (64x64), async staging, token GEMMs ----------------
template<int RELU, int OUTF32>
__global__ __launch_bounds__(256) void gemm64(const u16* __restrict__ A,
                                              const u16* __restrict__ WT,
                                              const float* __restrict__ bias,
                                              void* __restrict__ Cv,
                                              int Kd, int Nd){
  __shared__ u16 As[64][32];
  __shared__ u16 Bs[64][32];
  const int t = threadIdx.x;
  const int bm = blockIdx.y << 6;
  const int bn = blockIdx.x << 6;
  const int wave = t >> 6;
  const int lane = t & 63;
  const int wm = (wave & 1) << 5;
  const int wn = (wave >> 1) << 5;
  const int lm = lane & 15;
  const int lk = (lane >> 4) << 3;
  u16* AsF = &As[0][0];
  u16* BsF = &Bs[0][0];
  const int wbase = wave << 6;
  f32x4 acc[2][2] = {};
  for (int k0 = 0; k0 < Kd; k0 += 32){
    {
      int r = t >> 2;
      int c = (t & 3) << 3;
      int dst = wbase << 3;
      ld_g2l(A  + (size_t)(bm + r) * Kd + k0 + c, AsF + dst);
      ld_g2l(WT + (size_t)(bn + r) * Kd + k0 + c, BsF + dst);
    }
    __syncthreads();
    short8 af[2], bfr[2];
#pragma unroll
    for (int mt = 0; mt < 2; mt++) af[mt] = *(const short8*)&As[wm + (mt << 4) + lm][lk];
#pragma unroll
    for (int nt = 0; nt < 2; nt++) bfr[nt] = *(const short8*)&Bs[wn + (nt << 4) + lm][lk];
#pragma unroll
    for (int mt = 0; mt < 2; mt++)
#pragma unroll
      for (int nt = 0; nt < 2; nt++)
        acc[mt][nt] = __builtin_amdgcn_mfma_f32_16x16x32_bf16(af[mt], bfr[nt], acc[mt][nt], 0, 0, 0);
    __syncthreads();
  }
#pragma unroll
  for (int nt = 0; nt < 2; nt++){
    int n = bn + wn + (nt << 4) + lm;
    float bia = bias[n];
#pragma unroll
    for (int mt = 0; mt < 2; mt++){
#pragma unroll
      for (int r2 = 0; r2 < 4; r2++){
        int m = bm + wm + (mt << 4) + ((lane >> 4) << 2) + r2;
        float v = acc[mt][nt][r2] + bia;
        if (RELU) v = fmaxf(v, 0.0f);
        if (OUTF32) ((float*)Cv)[(size_t)m * Nd + n] = v;
        else        ((u16*)Cv)[(size_t)m * Nd + n] = f2bf(v);
      }
    }
  }
}

// ---------------- GEMM + fused max-pool (128x128), async staging ----------------
__global__ __launch_bounds__(256) void gemm_pool(const u16* __restrict__ A,
                                                 const u16* __restrict__ WT,
                                                 const float* __restrict__ bias,
                                                 u16* __restrict__ pooled,
                                                 int Kd, int Nd, int groupBase){
  __shared__ u16 As[128][32];
  __shared__ u16 Bs[128][32];
  const int t = threadIdx.x;
  const int bm = blockIdx.y << 7;
  const int bn = blockIdx.x << 7;
  const int wave = t >> 6;
  const int lane = t & 63;
  const int wm = (wave & 1) << 6;
  const int wn = (wave >> 1) << 6;
  const int lm = lane & 15;
  const int lk = (lane >> 4) << 3;
  u16* AsF = &As[0][0];
  u16* BsF = &Bs[0][0];
  const int wbase = wave << 6;
  f32x4 acc[4][4] = {};
  for (int k0 = 0; k0 < Kd; k0 += 32){
#pragma unroll
    for (int it = 0; it < 2; it++){
      int slot = t + (it << 8);
      int r = slot >> 2;
      int c = (slot & 3) << 3;
      int dst = (wbase + (it << 8)) << 3;
      ld_g2l(A  + (size_t)(bm + r) * Kd + k0 + c, AsF + dst);
      ld_g2l(WT + (size_t)(bn + r) * Kd + k0 + c, BsF + dst);
    }
    __syncthreads();
    short8 af[4], bfr[4];
#pragma unroll
    for (int mt = 0; mt < 4; mt++) af[mt] = *(const short8*)&As[wm + (mt << 4) + lm][lk];
#pragma unroll
    for (int nt = 0; nt < 4; nt++) bfr[nt] = *(const short8*)&Bs[wn + (nt << 4) + lm][lk];
#pragma unroll
    for (int mt = 0; mt < 4; mt++)
#pragma unroll
      for (int nt = 0; nt < 4; nt++)
        acc[mt][nt] = __builtin_amdgcn_mfma_f32_16x16x32_bf16(af[mt], bfr[nt], acc[mt][nt], 0, 0, 0);
    __syncthreads();
  }
  // each (mt) tile's 16 rows are exactly one pooling group
#pragma unroll
  for (int nt = 0; nt < 4; nt++){
    int n = bn + wn + (nt << 4) + lm;
    float bia = bias[n];
#pragma unroll
    for (int mt = 0; mt < 4; mt++){
      f32x4 a = acc[mt][nt];
      float v = fmaxf(fmaxf(a[0], a[1]), fmaxf(a[2], a[3]));
      v = fmaxf(v, __shfl_xor(v, 16));
      v = fmaxf(v, __shfl_xor(v, 32));
      if ((lane >> 4) == 0){
        int g = groupBase + (bm >> 4) + (wm >> 4) + mt;
        pooled[(size_t)g * Nd + n] = f2bf(v + bia);
      }
    }
  }
}

// ---------------- tier fallback (f32) ----------------
__global__ __launch_bounds__(256) void fill_diag(float* __restrict__ out, size_t out_elems){
  size_t i = (size_t)blockIdx.x * 256 + threadIdx.x;
  if (i >= out_elems) return;
  size_t maskStart = (size_t)B_ * M_ * D_ + (size_t)B_ * M_ * 4;
  out[i] = (i >= maskStart) ? 1.0f : 0.0f;
}

extern "C" void kernel_launch(void* const* d_in, const int* in_sizes, int n_in,
                              void* d_out, int out_size, void* d_ws, size_t ws_size,
                              hipStream_t stream){
  (void)in_sizes; (void)n_in;
  const float* coords   = (const float*)d_in[0];
  const float* features = (const float*)d_in[1];
  const float* W0 = (const float*)d_in[2];  const float* b0 = (const float*)d_in[3];
  const float* W1 = (const float*)d_in[4];  const float* b1 = (const float*)d_in[5];
  const float* W2 = (const float*)d_in[6];  const float* b2 = (const float*)d_in[7];
  const float* W3 = (const float*)d_in[8];  const float* b3 = (const float*)d_in[9];
  const float* Wn0 = (const float*)d_in[10]; const float* bn0 = (const float*)d_in[11];
  const float* Wn1 = (const float*)d_in[12]; const float* bn1 = (const float*)d_in[13];
  float* out = (float*)d_out;
  const size_t out_elems = (size_t)out_size;

  char* ws = (char*)d_ws;
  const size_t o_cent = 0;            // 16,384 (FPS order)
  const size_t o_cntS = 16384;        // 16,384 (time order)
  const size_t o_knn  = 32768;        // 65,536 -> 98,304
  const size_t o_Wb   = 131072;       // 4,587,520 bf16 W1t..Wn1t (transposed)
  const size_t o_pool = 4718592;      // 1,572,864 bf16 [1024,768]
  const size_t o_t1   = 6291456;      // 1,572,864
  const size_t o_chunk= 7864320;      // regA (R*1536 B) + regB (R*1024 B)
  const int ROWS = B_ * M_ * K_;      // 16384

  int R = 16384;
  while (R > 128 && o_chunk + (size_t)R * 2560 > ws_size) R >>= 1;
  if (d_ws == nullptr || o_chunk + (size_t)R * 2560 > ws_size){
    fill_diag<<<(int)((out_elems + 255) / 256), 256, 0, stream>>>(out, out_elems);
    return;
  }

  float* cent_fps    = (float*)(ws + o_cent);
  float* cent_sorted = (float*)(ws + o_cntS);
  int*   knn         = (int*)(ws + o_knn);
  u16* Wb   = (u16*)(ws + o_Wb);
  u16* W1t  = Wb;               u16* W2t  = Wb + 131072;
  u16* W3t  = Wb + 524288;      u16* Wn0t = Wb + 1114112;
  u16* Wn1t = Wb + 1703936;
  u16* pooled = (u16*)(ws + o_pool);
  u16* t1     = (u16*)(ws + o_t1);
  u16* regA   = (u16*)(ws + o_chunk);                      // h1 [R,256] then h3 [R,768]
  u16* regB   = (u16*)(ws + o_chunk + (size_t)R * 1536);   // h2 [R,512]

  conv_all<<<560, 256, 0, stream>>>(W1, W2, W3, Wn0, Wn1, Wb);
  fps_block<<<B_, 512, 0, stream>>>(coords, cent_fps);
  rank_scatter<<<B_, 128, 0, stream>>>(cent_fps, cent_sorted, out, out_elems);
  knn_kernel<<<B_ * M_, KNT, 0, stream>>>(coords, cent_sorted, knn);

  for (int rowBase = 0; rowBase < ROWS; rowBase += R){
    gather_l0<<<R / 32, 256, 0, stream>>>(features, knn, W0, b0, regA, rowBase);
    gemm_bf16<1,0><<<dim3(4, R / 128), 256, 0, stream>>>(regA, W1t, b1, regB, 256, 512);
    gemm_bf16<1,0><<<dim3(6, R / 128), 256, 0, stream>>>(regB, W2t, b2, regA, 512, 768);
    gemm_pool<<<dim3(6, R / 128), 256, 0, stream>>>(regA, W3t, b3, pooled, 768, 768, rowBase >> 4);
  }

  gemm64<1,0><<<dim3(12, (B_ * M_) / 64), 256, 0, stream>>>(pooled, Wn0t, bn0, t1, 768, 768);
  gemm64<0,1><<<dim3(12, (B_ * M_) / 64), 256, 0, stream>>>(t1, Wn1t, bn1, out, 768, 768);
}

// Round 11
// 497.955 us; speedup vs baseline: 1.1633x; 1.0339x over previous
//
#include <hip/hip_runtime.h>

#define B_ 8
#define N_ 16384
#define F_ 6
#define M_ 128
#define K_ 16
#define D_ 768

typedef unsigned short u16;
typedef unsigned int u32;
typedef unsigned long long u64;
typedef __attribute__((ext_vector_type(8))) short short8;
typedef __attribute__((ext_vector_type(4))) float f32x4;
typedef __attribute__((ext_vector_type(2))) float f32x2;

__device__ __forceinline__ u16 f2bf(float f){
  union { float f; u32 i; } v; v.f = f;
  u32 x = v.i;
  u32 r = x + 0x7FFFu + ((x >> 16) & 1u);
  return (u16)(r >> 16);
}

// async 16B global->LDS (dest = wave-uniform base + lane*16)
__device__ __forceinline__ void ld_g2l(const u16* g, u16* l){
  __builtin_amdgcn_global_load_lds((const __attribute__((address_space(1))) u32*)g,
                                   (__attribute__((address_space(3))) u32*)l, 16, 0, 0);
}

// VOLATILE asm 16B load: result cannot be rematerialized from memory by LLVM.
__device__ __forceinline__ f32x4 ld_x4(const float* p){
  f32x4 r;
  asm volatile("global_load_dwordx4 %0, %1, off" : "=v"(r) : "v"(p) : "memory");
  return r;
}

// DPP self-max/min steps: full-rate VALU — no LDS, no lgkmcnt. Chain
// {row_shr:1,2,4,8, row_bcast:15, row_bcast:31} leaves the wave result in lane 63
// (harness-verified in rounds 6/7/10 fps).
template<int CTRL>
__device__ __forceinline__ float dppmax(float v){
  union { float f; int i; } a, r;
  a.f = v;
  r.i = __builtin_amdgcn_update_dpp(a.i, a.i, CTRL, 0xF, 0xF, false);
  return fmaxf(v, r.f);
}
template<int CTRL>
__device__ __forceinline__ float dppmin(float v){
  union { float f; int i; } a, r;
  a.f = v;
  r.i = __builtin_amdgcn_update_dpp(a.i, a.i, CTRL, 0xF, 0xF, false);
  return fminf(v, r.f);
}
template<int CTRL>
__device__ __forceinline__ int dppimin(int v){
  int r = __builtin_amdgcn_update_dpp(v, v, CTRL, 0xF, 0xF, false);
  return (r < v) ? r : v;
}

// ---------------- FUSED: FPS (blocks 0..7) + weight conversion (blocks 8..567) ----------------
// FPS side = round-7 best-measured form (248us): p[32] quads volatile-pinned, single
// vmcnt drain, DPP wave-argmax + ballot + scalar combine, 1 barrier/step.
// NEW: (a) per-step centroid stashed in LDS carr[] by t==0; after the step loop the
// block does rank_scatter's stable time-sort in-place (saves a launch + global round
// trip). (b) conv blocks convert W1..Wn1 f32->bf16 transposed on the 248 idle CUs,
// fully hidden under FPS's ~250us shadow (saves the conv_all dispatch).
#define FPT 32   // fps: points per thread (512 thr)
__global__ __launch_bounds__(512)
void fps_conv(const float* __restrict__ coords,
              float* __restrict__ cent_sorted,
              float* __restrict__ out, size_t out_elems,
              const float* __restrict__ W1, const float* __restrict__ W2,
              const float* __restrict__ W3, const float* __restrict__ Wn0,
              const float* __restrict__ Wn1, u16* __restrict__ Wb){
#pragma clang fp contract(off)
  __shared__ u16 tile[64][65];       // conv branch (8.3 KB)
  __shared__ f32x4 carr[M_];         // fps: centroid per step (2 KB)
  __shared__ float swv[2][8];
  __shared__ int   swi[2][8];
  int blk = blockIdx.x;
  int t = threadIdx.x;

  if (blk >= 8){
    // ---------------- weight conversion branch (512 threads) ----------------
    int cblk = blk - 8;
    const float* W; u16* WT; int K, N, lb;
    if      (cblk < 32)  { W = W1;  WT = Wb;           K = 256; N = 512; lb = cblk; }
    else if (cblk < 128) { W = W2;  WT = Wb + 131072;  K = 512; N = 768; lb = cblk - 32; }
    else if (cblk < 272) { W = W3;  WT = Wb + 524288;  K = 768; N = 768; lb = cblk - 128; }
    else if (cblk < 416) { W = Wn0; WT = Wb + 1114112; K = 768; N = 768; lb = cblk - 272; }
    else                 { W = Wn1; WT = Wb + 1703936; K = 768; N = 768; lb = cblk - 416; }
    int tiles_n = N >> 6;
    int tk = lb / tiles_n, tn = lb % tiles_n;
    int k0 = tk << 6, n0 = tn << 6;
#pragma unroll
    for (int q = 0; q < 8; q++){
      int idx = q * 512 + t;
      int kk = idx >> 6, nn = idx & 63;
      tile[kk][nn] = f2bf(W[(size_t)(k0 + kk) * N + n0 + nn]);
    }
    __syncthreads();
#pragma unroll
    for (int q = 0; q < 8; q++){
      int idx = q * 512 + t;
      int nn = idx >> 6, kk = idx & 63;
      WT[(size_t)(n0 + nn) * K + k0 + kk] = tile[kk][nn];
    }
    return;
  }

  // ---------------- FPS branch (round-7 verbatim core) ----------------
  int b = blk;
  int lane = t & 63, wave = t >> 6;
  const float* cb = coords + (size_t)b * N_ * 5;
  const int base = t << 5;                       // first point index owned by this thread
  f32x4 p[FPT];
#pragma unroll
  for (int k = 0; k < FPT; k++){
    p[k] = ld_x4(cb + (size_t)(base + k) * 5 + 1);   // (x,y,z,w) of point base+k
  }
  float md[FPT];
#pragma unroll
  for (int k = 0; k < FPT; k++) md[k] = 1e30f;
  asm volatile("s_waitcnt vmcnt(0)" ::: "memory");   // drain the asm loads
  __builtin_amdgcn_sched_barrier(0);                 // rule #18: pin uses after the wait
  float cx = cb[1], cy = cb[2], cz = cb[3], ct = cb[4];
  if (t == 0) carr[0] = (f32x4){cx, cy, cz, ct};
  for (int step = 1; step < M_; step++){
    float bv = -1.0f; int bl = 0;
#pragma unroll
    for (int k = 0; k < FPT; k++){
      f32x2 xy = (f32x2){p[k][0], p[k][1]};
      f32x2 zw = (f32x2){p[k][2], p[k][3]};
      float dx = xy[0] - cx;
      float dy = xy[1] - cy;
      float dz = zw[0] - cz;
      float dw = zw[1] - ct;
      float s = ((dx*dx + dy*dy) + dz*dz) + dw*dw;   // reference rounding order
      float m = fminf(s, md[k]);
      md[k] = m;
      if (m > bv){ bv = m; bl = k; }                 // ascending-index first-max
    }
    int bi = base + bl;                              // global point index
    // ---- wave argmax: 6 DPP fmax levels -> lane 63 holds wave max ----
    float r = bv;
    r = dppmax<0x111>(r);        // row_shr:1
    r = dppmax<0x112>(r);        // row_shr:2
    r = dppmax<0x114>(r);        // row_shr:4
    r = dppmax<0x118>(r);        // row_shr:8
    r = dppmax<0x142>(r);        // row_bcast:15
    r = dppmax<0x143>(r);        // row_bcast:31
    union { float f; int i; } rm; rm.f = r;
    union { int i; float f; } wmu; wmu.i = __builtin_amdgcn_readlane(rm.i, 63);
    float wmax = wmu.f;                              // uniform (SGPR)
    u64 wmask = __ballot(bv == wmax);
    int srcL = (int)__ffsll((unsigned long long)wmask) - 1;  // lowest lane = lowest index
    int wbi = __builtin_amdgcn_readlane(bi, srcL);   // uniform winner index of this wave
    int par = step & 1;
    if (lane == 0){ swv[par][wave] = wmax; swi[par][wave] = wbi; }
    __syncthreads();                                 // only barrier per step
    // ---- block combine: broadcast LDS reads + uniform serial strict-greater scan ----
    float fv = swv[par][0]; int fi = swi[par][0];
#pragma unroll
    for (int w = 1; w < 8; w++){
      float v = swv[par][w];
      int  iw = swi[par][w];
      if (v > fv){ fv = v; fi = iw; }                // strict > keeps lowest wave (= lowest index)
    }
    int widx = __builtin_amdgcn_readfirstlane(fi);
    size_t wb = (size_t)widx * 5;
    cx = cb[wb+1]; cy = cb[wb+2]; cz = cb[wb+3]; ct = cb[wb+4];
    if (t == 0) carr[step] = (f32x4){cx, cy, cz, ct};
  }
  // ---- fused rank_scatter: stable argsort by centroid time (column 3) ----
  __syncthreads();
  if (t < M_){
    f32x4 row = carr[t];
    float w = row[3];
    int rank = 0;
    for (int j = 0; j < M_; j++){
      float tj = carr[j][3];
      if (tj < w || (tj == w && j < t)) rank++;      // stable argsort semantics
    }
    float* dst = cent_sorted + ((size_t)b * M_ + rank) * 4;
    dst[0]=row[0]; dst[1]=row[1]; dst[2]=row[2]; dst[3]=w;
    size_t co = (size_t)B_ * M_ * D_ + ((size_t)b * M_ + rank) * 4;
    if (co + 3 < out_elems){
      out[co+0]=row[0]; out[co+1]=row[1]; out[co+2]=row[2]; out[co+3]=w;
    }
    size_t mo = (size_t)B_ * M_ * D_ + (size_t)B_ * M_ * 4 + (size_t)b * M_ + t;
    if (mo < out_elems) out[mo] = 1.0f;              // mask = True -> 1.0f
  }
}

// ---------------- kNN: f32, np op order, stable-min extraction; DPP wave reduce ----------------
#define KNT 512
#define KPT 32
__global__ __launch_bounds__(512) void knn_kernel(const float* __restrict__ coords,
                                                  const float* __restrict__ cent,
                                                  int* __restrict__ knn){
#pragma clang fp contract(off)
  int cm = blockIdx.x;
  int b = cm >> 7;
  const float* cb = coords + (size_t)b * N_ * 5;
  int t = threadIdx.x;
  float cx=cent[cm*4+0], cy=cent[cm*4+1], cz=cent[cm*4+2], ct=cent[cm*4+3];
  float dist[KPT];
#pragma unroll
  for (int j = 0; j < KPT; j++){
    size_t i = t + j * KNT;
    float dx=cb[i*5+1]-cx, dy=cb[i*5+2]-cy, dz=cb[i*5+3]-cz, dw=cb[i*5+4]-ct;
    float d = ((dx*dx + dy*dy) + dz*dz) + dw*dw;
    dist[j] = sqrtf(d);                            // IEEE f32 sqrt = np.sqrt(f32)
  }
  __shared__ float s_wv[8];
  __shared__ int s_wi[8];
  __shared__ int s_bi;
  for (int r = 0; r < K_; r++){
    float bv = 3e38f; int bi = 1 << 30;
#pragma unroll
    for (int j = 0; j < KPT; j++){
      int i = t + j * KNT;
      float v = dist[j];
      if (v < bv){ bv = v; bi = i; }               // first-min kept (ascending own indices)
    }
    // ---- wave reduce, exact (min value, then min INDEX among ties) ----
    // value min via DPP chain; then ties enter an integer index-min DPP chain
    // (lane order != index order here, so lane tie-break would be wrong).
    float rv = bv;
    rv = dppmin<0x111>(rv);
    rv = dppmin<0x112>(rv);
    rv = dppmin<0x114>(rv);
    rv = dppmin<0x118>(rv);
    rv = dppmin<0x142>(rv);
    rv = dppmin<0x143>(rv);
    union { float f; int i; } rmu; rmu.f = rv;
    union { int i; float f; } wmn; wmn.i = __builtin_amdgcn_readlane(rmu.i, 63);
    float wmin = wmn.f;                            // uniform wave min value
    int cand = (bv == wmin) ? bi : 0x7FFFFFFF;
    cand = dppimin<0x111>(cand);
    cand = dppimin<0x112>(cand);
    cand = dppimin<0x114>(cand);
    cand = dppimin<0x118>(cand);
    cand = dppimin<0x142>(cand);
    cand = dppimin<0x143>(cand);
    int wbi = __builtin_amdgcn_readlane(cand, 63); // lowest index among tied lanes
    if ((t & 63) == 0){ s_wv[t >> 6] = wmin; s_wi[t >> 6] = wbi; }
    __syncthreads();
    if (t == 0){
      float fv = s_wv[0]; int fi = s_wi[0];
      for (int w = 1; w < 8; w++){
        float wv = s_wv[w]; int wi = s_wi[w];
        if (wv < fv || (wv == fv && wi < fi)){ fv = wv; fi = wi; }
      }
      s_bi = fi;
      knn[(size_t)cm * K_ + r] = fi & (N_ - 1);
    }
    __syncthreads();
    int wi = s_bi;
#pragma unroll
    for (int j = 0; j < KPT; j++){
      if (t + j * KNT == wi) dist[j] = 3e38f;
    }
  }
}

// ---------------- gather + layer0: 32 rows/block, W0/b0/features LDS-staged ----------------
__global__ __launch_bounds__(256) void gather_l0(const float* __restrict__ feat,
                                                 const int* __restrict__ knn,
                                                 const float* __restrict__ W0,
                                                 const float* __restrict__ b0,
                                                 u16* __restrict__ h1,
                                                 int rowBase){
  __shared__ float sW[F_][256];
  __shared__ float sb[256];
  __shared__ float sfa[32][F_];
  int t = threadIdx.x;
#pragma unroll
  for (int k = 0; k < F_; k++) sW[k][t] = W0[k * 256 + t];
  sb[t] = b0[t];
  if (t < 32 * F_){
    int r = t / F_, k = t % F_;
    int grow = rowBase + blockIdx.x * 32 + r;
    int bb = grow >> 11;                          // /(M*K)=2048
    int idx = knn[grow] & (N_ - 1);
    sfa[r][k] = feat[((size_t)bb * N_ + idx) * F_ + k];
  }
  __syncthreads();
#pragma unroll 4
  for (int r = 0; r < 32; r++){
    float acc = sb[t];
#pragma unroll
    for (int k = 0; k < F_; k++) acc = fmaf(sfa[r][k], sW[k][t], acc);
    int lrow = blockIdx.x * 32 + r;
    h1[(size_t)lrow * 256 + t] = f2bf(fmaxf(acc, 0.0f));
  }
}

// ---------------- bf16 MFMA GEMM (128x128), async global->LDS staging ----------------
// Unpadded [128][32] rows (64B): dest = wave-uniform base + lane*16 (m97 layout).
template<int RELU, int OUTF32>
__global__ __launch_bounds__(256) void gemm_bf16(const u16* __restrict__ A,
                                                 const u16* __restrict__ WT,
                                                 const float* __restrict__ bias,
                                                 void* __restrict__ Cv,
                                                 int Kd, int Nd){
  __shared__ u16 As[128][32];
  __shared__ u16 Bs[128][32];
  const int t = threadIdx.x;
  const int bm = blockIdx.y << 7;
  const int bn = blockIdx.x << 7;
  const int wave = t >> 6;
  const int lane = t & 63;
  const int wm = (wave & 1) << 6;
  const int wn = (wave >> 1) << 6;
  const int lm = lane & 15;
  const int lk = (lane >> 4) << 3;
  u16* AsF = &As[0][0];
  u16* BsF = &Bs[0][0];
  const int wbase = wave << 6;               // t - lane
  f32x4 acc[4][4] = {};
  for (int k0 = 0; k0 < Kd; k0 += 32){
#pragma unroll
    for (int it = 0; it < 2; it++){
      int slot = t + (it << 8);
      int r = slot >> 2;
      int c = (slot & 3) << 3;
      int dst = (wbase + (it << 8)) << 3;    // u16 elements; +lane*16B by HW
      ld_g2l(A  + (size_t)(bm + r) * Kd + k0 + c, AsF + dst);
      ld_g2l(WT + (size_t)(bn + r) * Kd + k0 + c, BsF + dst);
    }
    __syncthreads();
    short8 af[4], bfr[4];
#pragma unroll
    for (int mt = 0; mt < 4; mt++) af[mt] = *(const short8*)&As[wm + (mt << 4) + lm][lk];
#pragma unroll
    for (int nt = 0; nt < 4; nt++) bfr[nt] = *(const short8*)&Bs[wn + (nt << 4) + lm][lk];
#pragma unroll
    for (int mt = 0; mt < 4; mt++)
#pragma unroll
      for (int nt = 0; nt < 4; nt++)
        acc[mt][nt] = __builtin_amdgcn_mfma_f32_16x16x32_bf16(af[mt], bfr[nt], acc[mt][nt], 0, 0, 0);
    __syncthreads();
  }
#pragma unroll
  for (int nt = 0; nt < 4; nt++){
    int n = bn + wn + (nt << 4) + lm;
    float bia = bias[n];
#pragma unroll
    for (int mt = 0; mt < 4; mt++){
#pragma unroll
      for (int r2 = 0; r2 < 4; r2++){
        int m = bm + wm + (mt << 4) + ((lane >> 4) << 2) + r2;
        float v = acc[mt][nt][r2] + bia;
        if (RELU) v = fmaxf(v, 0.0f);
        if (OUTF32) ((float*)Cv)[(size_t)m * Nd + n] = v;
        else        ((u16*)Cv)[(size_t)m * Nd + n] = f2bf(v);
      }
    }
  }
}

// ---------------- bf16 MFMA GEMM (64x64), async staging, token GEMMs ----------------
template<int RELU, int OUTF32>
__global__ __launch_bounds__(256) void gemm64(const u16* __restrict__ A,
                                              const u16* __restrict__ WT,
                                              const float* __restrict__ bias,
                                              void* __restrict__ Cv,
                                              int Kd, int Nd){
  __shared__ u16 As[64][32];
  __shared__ u16 Bs[64][32];
  const int t = threadIdx.x;
  const int bm = blockIdx.y << 6;
  const int bn = blockIdx.x << 6;
  const int wave = t >> 6;
  const int lane = t & 63;
  const int wm = (wave & 1) << 5;
  const int wn = (wave >> 1) << 5;
  const int lm = lane & 15;
  const int lk = (lane >> 4) << 3;
  u16* AsF = &As[0][0];
  u16* BsF = &Bs[0][0];
  const int wbase = wave << 6;
  f32x4 acc[2][2] = {};
  for (int k0 = 0; k0 < Kd; k0 += 32){
    {
      int r = t >> 2;
      int c = (t & 3) << 3;
      int dst = wbase << 3;
      ld_g2l(A  + (size_t)(bm + r) * Kd + k0 + c, AsF + dst);
      ld_g2l(WT + (size_t)(bn + r) * Kd + k0 + c, BsF + dst);
    }
    __syncthreads();
    short8 af[2], bfr[2];
#pragma unroll
    for (int mt = 0; mt < 2; mt++) af[mt] = *(const short8*)&As[wm + (mt << 4) + lm][lk];
#pragma unroll
    for (int nt = 0; nt < 2; nt++) bfr[nt] = *(const short8*)&Bs[wn + (nt << 4) + lm][lk];
#pragma unroll
    for (int mt = 0; mt < 2; mt++)
#pragma unroll
      for (int nt = 0; nt < 2; nt++)
        acc[mt][nt] = __builtin_amdgcn_mfma_f32_16x16x32_bf16(af[mt], bfr[nt], acc[mt][nt], 0, 0, 0);
    __syncthreads();
  }
#pragma unroll
  for (int nt = 0; nt < 2; nt++){
    int n = bn + wn + (nt << 4) + lm;
    float bia = bias[n];
#pragma unroll
    for (int mt = 0; mt < 2; mt++){
#pragma unroll
      for (int r2 = 0; r2 < 4; r2++){
        int m = bm + wm + (mt << 4) + ((lane >> 4) << 2) + r2;
        float v = acc[mt][nt][r2] + bia;
        if (RELU) v = fmaxf(v, 0.0f);
        if (OUTF32) ((float*)Cv)[(size_t)m * Nd + n] = v;
        else        ((u16*)Cv)[(size_t)m * Nd + n] = f2bf(v);
      }
    }
  }
}

// ---------------- GEMM + fused max-pool (128x128), async staging ----------------
__global__ __launch_bounds__(256) void gemm_pool(const u16* __restrict__ A,
                                                 const u16* __restrict__ WT,
                                                 const float* __restrict__ bias,
                                                 u16* __restrict__ pooled,
                                                 int Kd, int Nd, int groupBase){
  __shared__ u16 As[128][32];
  __shared__ u16 Bs[128][32];
  const int t = threadIdx.x;
  const int bm = blockIdx.y << 7;
  const int bn = blockIdx.x << 7;
  const int wave = t >> 6;
  const int lane = t & 63;
  const int wm = (wave & 1) << 6;
  const int wn = (wave >> 1) << 6;
  const int lm = lane & 15;
  const int lk = (lane >> 4) << 3;
  u16* AsF = &As[0][0];
  u16* BsF = &Bs[0][0];
  const int wbase = wave << 6;
  f32x4 acc[4][4] = {};
  for (int k0 = 0; k0 < Kd; k0 += 32){
#pragma unroll
    for (int it = 0; it < 2; it++){
      int slot = t + (it << 8);
      int r = slot >> 2;
      int c = (slot & 3) << 3;
      int dst = (wbase + (it << 8)) << 3;
      ld_g2l(A  + (size_t)(bm + r) * Kd + k0 + c, AsF + dst);
      ld_g2l(WT + (size_t)(bn + r) * Kd + k0 + c, BsF + dst);
    }
    __syncthreads();
    short8 af[4], bfr[4];
#pragma unroll
    for (int mt = 0; mt < 4; mt++) af[mt] = *(const short8*)&As[wm + (mt << 4) + lm][lk];
#pragma unroll
    for (int nt = 0; nt < 4; nt++) bfr[nt] = *(const short8*)&Bs[wn + (nt << 4) + lm][lk];
#pragma unroll
    for (int mt = 0; mt < 4; mt++)
#pragma unroll
      for (int nt = 0; nt < 4; nt++)
        acc[mt][nt] = __builtin_amdgcn_mfma_f32_16x16x32_bf16(af[mt], bfr[nt], acc[mt][nt], 0, 0, 0);
    __syncthreads();
  }
  // each (mt) tile's 16 rows are exactly one pooling group
#pragma unroll
  for (int nt = 0; nt < 4; nt++){
    int n = bn + wn + (nt << 4) + lm;
    float bia = bias[n];
#pragma unroll
    for (int mt = 0; mt < 4; mt++){
      f32x4 a = acc[mt][nt];
      float v = fmaxf(fmaxf(a[0], a[1]), fmaxf(a[2], a[3]));
      v = fmaxf(v, __shfl_xor(v, 16));
      v = fmaxf(v, __shfl_xor(v, 32));
      if ((lane >> 4) == 0){
        int g = groupBase + (bm >> 4) + (wm >> 4) + mt;
        pooled[(size_t)g * Nd + n] = f2bf(v + bia);
      }
    }
  }
}

// ---------------- tier fallback (f32) ----------------
__global__ __launch_bounds__(256) void fill_diag(float* __restrict__ out, size_t out_elems){
  size_t i = (size_t)blockIdx.x * 256 + threadIdx.x;
  if (i >= out_elems) return;
  size_t maskStart = (size_t)B_ * M_ * D_ + (size_t)B_ * M_ * 4;
  out[i] = (i >= maskStart) ? 1.0f : 0.0f;
}

extern "C" void kernel_launch(void* const* d_in, const int* in_sizes, int n_in,
                              void* d_out, int out_size, void* d_ws, size_t ws_size,
                              hipStream_t stream){
  (void)in_sizes; (void)n_in;
  const float* coords   = (const float*)d_in[0];
  const float* features = (const float*)d_in[1];
  const float* W0 = (const float*)d_in[2];  const float* b0 = (const float*)d_in[3];
  const float* W1 = (const float*)d_in[4];  const float* b1 = (const float*)d_in[5];
  const float* W2 = (const float*)d_in[6];  const float* b2 = (const float*)d_in[7];
  const float* W3 = (const float*)d_in[8];  const float* b3 = (const float*)d_in[9];
  const float* Wn0 = (const float*)d_in[10]; const float* bn0 = (const float*)d_in[11];
  const float* Wn1 = (const float*)d_in[12]; const float* bn1 = (const float*)d_in[13];
  float* out = (float*)d_out;
  const size_t out_elems = (size_t)out_size;

  char* ws = (char*)d_ws;
  const size_t o_cent = 0;            // 16,384 (unused, kept for layout stability)
  const size_t o_cntS = 16384;        // 16,384 (time order)
  const size_t o_knn  = 32768;        // 65,536 -> 98,304
  const size_t o_Wb   = 131072;       // 4,587,520 bf16 W1t..Wn1t (transposed)
  const size_t o_pool = 4718592;      // 1,572,864 bf16 [1024,768]
  const size_t o_t1   = 6291456;      // 1,572,864
  const size_t o_chunk= 7864320;      // regA (R*1536 B) + regB (R*1024 B)
  const int ROWS = B_ * M_ * K_;      // 16384
  (void)o_cent;

  int R = 16384;
  while (R > 128 && o_chunk + (size_t)R * 2560 > ws_size) R >>= 1;
  if (d_ws == nullptr || o_chunk + (size_t)R * 2560 > ws_size){
    fill_diag<<<(int)((out_elems + 255) / 256), 256, 0, stream>>>(out, out_elems);
    return;
  }

  float* cent_sorted = (float*)(ws + o_cntS);
  int*   knn         = (int*)(ws + o_knn);
  u16* Wb   = (u16*)(ws + o_Wb);
  u16* W1t  = Wb;               u16* W2t  = Wb + 131072;
  u16* W3t  = Wb + 524288;      u16* Wn0t = Wb + 1114112;
  u16* Wn1t = Wb + 1703936;
  u16* pooled = (u16*)(ws + o_pool);
  u16* t1     = (u16*)(ws + o_t1);
  u16* regA   = (u16*)(ws + o_chunk);                      // h1 [R,256] then h3 [R,768]
  u16* regB   = (u16*)(ws + o_chunk + (size_t)R * 1536);   // h2 [R,512]

  // FPS (8 blocks, ~250us on 8 CUs) + weight conversion (560 blocks, hidden on idle CUs)
  // + fused rank_scatter in the FPS tail.
  fps_conv<<<568, 512, 0, stream>>>(coords, cent_sorted, out, out_elems,
                                    W1, W2, W3, Wn0, Wn1, Wb);
  knn_kernel<<<B_ * M_, KNT, 0, stream>>>(coords, cent_sorted, knn);

  for (int rowBase = 0; rowBase < ROWS; rowBase += R){
    gather_l0<<<R / 32, 256, 0, stream>>>(features, knn, W0, b0, regA, rowBase);
    gemm_bf16<1,0><<<dim3(4, R / 128), 256, 0, stream>>>(regA, W1t, b1, regB, 256, 512);
    gemm_bf16<1,0><<<dim3(6, R / 128), 256, 0, stream>>>(regB, W2t, b2, regA, 512, 768);
    gemm_pool<<<dim3(6, R / 128), 256, 0, stream>>>(regA, W3t, b3, pooled, 768, 768, rowBase >> 4);
  }

  gemm64<1,0><<<dim3(12, (B_ * M_) / 64), 256, 0, stream>>>(pooled, Wn0t, bn0, t1, 768, 768);
  gemm64<0,1><<<dim3(12, (B_ * M_) / 64), 256, 0, stream>>>(t1, Wn1t, bn1, out, 768, 768);
}